// Round 7
// baseline (501.855 us; speedup 1.0000x reference)
//
#include <hip/hip_runtime.h>

#define B_  8
#define L_  2048
#define C_  512
#define R_  256
#define H_  8
#define DK_ 64
#define HD_ 512
#define MASK_NEG (-32767.0f)

typedef __attribute__((ext_vector_type(8))) short short8;
typedef __attribute__((ext_vector_type(8))) unsigned short ushort8;
typedef __attribute__((ext_vector_type(4))) unsigned short ushort4_t;
typedef __attribute__((ext_vector_type(4))) float f32x4;
typedef unsigned short u16;

__device__ inline u16 bf16_rne(float x) {
    unsigned u = __float_as_uint(x);
    return (u16)((u + 0x7FFFu + ((u >> 16) & 1u)) >> 16);
}
// hi bf16 in low 16 bits, lo bf16 in high 16 bits
__device__ inline unsigned cvt_hl(float x) {
    u16 hh = bf16_rne(x);
    float hf = __uint_as_float(((unsigned)hh) << 16);
    u16 ll = bf16_rne(x - hf);
    return (unsigned)hh | ((unsigned)ll << 16);
}

struct Ptr3 { const void* p0; const void* p1; const void* p2; };

// ---------------- MFMA plane GEMM ----------------
// C = scale * A @ B via 3-term split MFMA (Ah@Bh + Ah@Bl + Al@Bh).
// AMODE: 0 = bf16 planes [M][K]; 2 = fp32 [M][K] (cvt on stage)
// BMODE: 0 = bf16 planes [N][K]
// EPI:   0 = store fp32 C*scale; 1 = atomicAdd sum offdiag(C)^2; 2 = store hi/lo planes
// Batch: z -> zb=z/divz, zh=z%divz. TRIPLE: zb picks pointer from Ptr3, else *sb strides.
template<int BN, int AMODE, int BMODE, int EPI, bool TRIPLE>
__global__ __launch_bounds__(256) void gemm_pl(
    Ptr3 aH, Ptr3 aL, Ptr3 bH, Ptr3 bL, Ptr3 cH, Ptr3 cL,
    int K, int lda, int ldb, int ldc, int divz,
    long long ash, long long bsh, long long csh,
    long long asb, long long bsb, long long csb,
    float scale, float* __restrict__ lossAcc)
{
    constexpr int NF = BN / 32;
    __shared__ u16 Ahs[64][40], Als[64][40];
    __shared__ u16 Bhs[BN][40], Bls[BN][40];
    __shared__ float red[4];

    const int z  = blockIdx.z;
    const int zb = z / divz, zh = z - zb * divz;
    const void* avH = TRIPLE ? (zb == 0 ? aH.p0 : zb == 1 ? aH.p1 : aH.p2) : aH.p0;
    const void* avL = TRIPLE ? (zb == 0 ? aL.p0 : zb == 1 ? aL.p1 : aL.p2) : aL.p0;
    const void* bvH = TRIPLE ? (zb == 0 ? bH.p0 : zb == 1 ? bH.p1 : bH.p2) : bH.p0;
    const void* bvL = TRIPLE ? (zb == 0 ? bL.p0 : zb == 1 ? bL.p1 : bL.p2) : bL.p0;
    void* cvH = (void*)(TRIPLE ? (zb == 0 ? cH.p0 : zb == 1 ? cH.p1 : cH.p2) : cH.p0);
    void* cvL = (void*)(TRIPLE ? (zb == 0 ? cL.p0 : zb == 1 ? cL.p1 : cL.p2) : cL.p0);
    const long long ao = (TRIPLE ? 0 : (long long)zb * asb) + (long long)zh * ash;
    const long long bo = (TRIPLE ? 0 : (long long)zb * bsb) + (long long)zh * bsh;
    const long long co = (TRIPLE ? 0 : (long long)zb * csb) + (long long)zh * csh;

    const u16*   AHg = (const u16*)avH + ao;
    const u16*   ALg = (const u16*)avL + ao;
    const float* Afg = (const float*)avH + ao;
    const u16*   BHg = (const u16*)bvH + bo;
    const u16*   BLg = (const u16*)bvL + bo;
    float* Cf  = (float*)cvH + co;
    u16*   CHg = (u16*)cvH + co;
    u16*   CLg = (u16*)cvL + co;

    const int m0 = blockIdx.y * 64, n0 = blockIdx.x * BN;
    const int tid = threadIdx.x;
    const int lane = tid & 63, w = tid >> 6;
    const int wrow = (w >> 1) * 32, wcol = (w & 1) * (BN / 2);
    const int l15 = lane & 15, lg = lane >> 4;

    f32x4 zero = {0.f, 0.f, 0.f, 0.f};
    f32x4 acc[2][NF];
    #pragma unroll
    for (int mf = 0; mf < 2; ++mf)
        #pragma unroll
        for (int nf = 0; nf < NF; ++nf) acc[mf][nf] = zero;

    for (int k0 = 0; k0 < K; k0 += 32) {
        // ---- stage A (64 x 32) ----
        if (AMODE == 0) {
            int row = tid >> 2, kc = (tid & 3) << 3;
            long long off = (long long)(m0 + row) * lda + (k0 + kc);
            *(ushort8*)&Ahs[row][kc] = *(const ushort8*)(AHg + off);
            *(ushort8*)&Als[row][kc] = *(const ushort8*)(ALg + off);
        } else { // AMODE == 2: fp32 [M][K]
            int row = tid >> 2, kc = (tid & 3) << 3;
            const float* s = Afg + (long long)(m0 + row) * lda + (k0 + kc);
            float4 v0 = *(const float4*)s, v1 = *(const float4*)(s + 4);
            unsigned p0 = cvt_hl(v0.x), p1 = cvt_hl(v0.y), p2 = cvt_hl(v0.z), p3 = cvt_hl(v0.w);
            unsigned p4 = cvt_hl(v1.x), p5 = cvt_hl(v1.y), p6 = cvt_hl(v1.z), p7 = cvt_hl(v1.w);
            ushort8 h, l;
            h[0]=(u16)p0; h[1]=(u16)p1; h[2]=(u16)p2; h[3]=(u16)p3;
            h[4]=(u16)p4; h[5]=(u16)p5; h[6]=(u16)p6; h[7]=(u16)p7;
            l[0]=(u16)(p0>>16); l[1]=(u16)(p1>>16); l[2]=(u16)(p2>>16); l[3]=(u16)(p3>>16);
            l[4]=(u16)(p4>>16); l[5]=(u16)(p5>>16); l[6]=(u16)(p6>>16); l[7]=(u16)(p7>>16);
            *(ushort8*)&Ahs[row][kc] = h;
            *(ushort8*)&Als[row][kc] = l;
        }
        // ---- stage B (BN x 32), planes [N][K] ----
        #pragma unroll
        for (int t = tid; t < BN * 4; t += 256) {
            int row = t >> 2, kc = (t & 3) << 3;
            long long off = (long long)(n0 + row) * ldb + (k0 + kc);
            *(ushort8*)&Bhs[row][kc] = *(const ushort8*)(BHg + off);
            *(ushort8*)&Bls[row][kc] = *(const ushort8*)(BLg + off);
        }
        __syncthreads();

        short8 a_h[2], a_l[2];
        a_h[0] = *(const short8*)&Ahs[wrow +      l15][lg * 8];
        a_h[1] = *(const short8*)&Ahs[wrow + 16 + l15][lg * 8];
        a_l[0] = *(const short8*)&Als[wrow +      l15][lg * 8];
        a_l[1] = *(const short8*)&Als[wrow + 16 + l15][lg * 8];
        #pragma unroll
        for (int nf = 0; nf < NF; ++nf) {
            short8 b_h = *(const short8*)&Bhs[wcol + nf * 16 + l15][lg * 8];
            short8 b_l = *(const short8*)&Bls[wcol + nf * 16 + l15][lg * 8];
            #pragma unroll
            for (int mf = 0; mf < 2; ++mf) {
                acc[mf][nf] = __builtin_amdgcn_mfma_f32_16x16x32_bf16(a_h[mf], b_h, acc[mf][nf], 0, 0, 0);
                acc[mf][nf] = __builtin_amdgcn_mfma_f32_16x16x32_bf16(a_h[mf], b_l, acc[mf][nf], 0, 0, 0);
                acc[mf][nf] = __builtin_amdgcn_mfma_f32_16x16x32_bf16(a_l[mf], b_h, acc[mf][nf], 0, 0, 0);
            }
        }
        __syncthreads();
    }

    if (EPI == 0) {
        #pragma unroll
        for (int mf = 0; mf < 2; ++mf)
            #pragma unroll
            for (int nf = 0; nf < NF; ++nf) {
                int row = m0 + wrow + mf * 16 + lg * 4;
                int col = n0 + wcol + nf * 16 + l15;
                #pragma unroll
                for (int j = 0; j < 4; ++j)
                    Cf[(long long)(row + j) * ldc + col] = acc[mf][nf][j] * scale;
            }
    } else if (EPI == 2) {
        #pragma unroll
        for (int mf = 0; mf < 2; ++mf)
            #pragma unroll
            for (int nf = 0; nf < NF; ++nf) {
                int row = m0 + wrow + mf * 16 + lg * 4;
                int col = n0 + wcol + nf * 16 + l15;
                #pragma unroll
                for (int j = 0; j < 4; ++j) {
                    unsigned p = cvt_hl(acc[mf][nf][j] * scale);
                    CHg[(long long)(row + j) * ldc + col] = (u16)p;
                    CLg[(long long)(row + j) * ldc + col] = (u16)(p >> 16);
                }
            }
    } else {
        float s = 0.0f;
        #pragma unroll
        for (int mf = 0; mf < 2; ++mf)
            #pragma unroll
            for (int nf = 0; nf < NF; ++nf) {
                int row = m0 + wrow + mf * 16 + lg * 4;
                int col = n0 + wcol + nf * 16 + l15;
                #pragma unroll
                for (int j = 0; j < 4; ++j)
                    if (row + j != col) { float c = acc[mf][nf][j]; s += c * c; }
            }
        #pragma unroll
        for (int o = 32; o; o >>= 1) s += __shfl_down(s, o, 64);
        if (lane == 0) red[w] = s;
        __syncthreads();
        if (tid == 0) atomicAdd(lossAcc, red[0] + red[1] + red[2] + red[3]);
    }
}

// ---------------- transpose kernels ----------------
// fp32 [M][N] -> fp32 [N][M], batched over z
__global__ __launch_bounds__(256) void xpose_f32(
    const float* __restrict__ in, float* __restrict__ out,
    int M, int N, long long ibs, long long obs)
{
    __shared__ float S[64][65];
    const float* ip = in + (long long)blockIdx.z * ibs;
    float* op = out + (long long)blockIdx.z * obs;
    int n0 = blockIdx.x * 64, m0 = blockIdx.y * 64;
    int t = threadIdx.x;
    int c4 = (t & 15) << 2, rq = t >> 4;
    #pragma unroll
    for (int p = 0; p < 4; ++p) {
        int r = p * 16 + rq;
        float4 v = *(const float4*)(ip + (long long)(m0 + r) * N + n0 + c4);
        S[r][c4+0]=v.x; S[r][c4+1]=v.y; S[r][c4+2]=v.z; S[r][c4+3]=v.w;
    }
    __syncthreads();
    #pragma unroll
    for (int p = 0; p < 4; ++p) {
        int nr = p * 16 + rq;
        float4 o;
        o.x = S[c4+0][nr]; o.y = S[c4+1][nr]; o.z = S[c4+2][nr]; o.w = S[c4+3][nr];
        *(float4*)(op + (long long)(n0 + nr) * M + m0 + c4) = o;
    }
}

// fp32 [M][N] -> bf16 hi/lo planes [N][M], batched over z
__global__ __launch_bounds__(256) void xpose_f32p(
    const float* __restrict__ in, u16* __restrict__ outH, u16* __restrict__ outL,
    int M, int N, long long ibs, long long obs)
{
    __shared__ float S[64][65];
    const float* ip = in + (long long)blockIdx.z * ibs;
    u16* opH = outH + (long long)blockIdx.z * obs;
    u16* opL = outL + (long long)blockIdx.z * obs;
    int n0 = blockIdx.x * 64, m0 = blockIdx.y * 64;
    int t = threadIdx.x;
    int c4 = (t & 15) << 2, rq = t >> 4;
    #pragma unroll
    for (int p = 0; p < 4; ++p) {
        int r = p * 16 + rq;
        float4 v = *(const float4*)(ip + (long long)(m0 + r) * N + n0 + c4);
        S[r][c4+0]=v.x; S[r][c4+1]=v.y; S[r][c4+2]=v.z; S[r][c4+3]=v.w;
    }
    __syncthreads();
    #pragma unroll
    for (int p = 0; p < 4; ++p) {
        int nr = p * 16 + rq;
        unsigned q0 = cvt_hl(S[c4+0][nr]), q1 = cvt_hl(S[c4+1][nr]);
        unsigned q2 = cvt_hl(S[c4+2][nr]), q3 = cvt_hl(S[c4+3][nr]);
        ushort4_t h, l;
        h[0]=(u16)q0; h[1]=(u16)q1; h[2]=(u16)q2; h[3]=(u16)q3;
        l[0]=(u16)(q0>>16); l[1]=(u16)(q1>>16); l[2]=(u16)(q2>>16); l[3]=(u16)(q3>>16);
        long long ob = (long long)(n0 + nr) * M + m0 + c4;
        *(ushort4_t*)(opH + ob) = h;
        *(ushort4_t*)(opL + ob) = l;
    }
}

// u16 planes [M][N] -> planes [N][M], batched over z
__global__ __launch_bounds__(256) void xpose_u16p(
    const u16* __restrict__ inH, const u16* __restrict__ inL,
    u16* __restrict__ outH, u16* __restrict__ outL,
    int M, int N, long long ibs, long long obs)
{
    __shared__ u16 SH[64][66], SL[64][66];
    const u16* ipH = inH + (long long)blockIdx.z * ibs;
    const u16* ipL = inL + (long long)blockIdx.z * ibs;
    u16* opH = outH + (long long)blockIdx.z * obs;
    u16* opL = outL + (long long)blockIdx.z * obs;
    int n0 = blockIdx.x * 64, m0 = blockIdx.y * 64;
    int t = threadIdx.x;
    int c4 = (t & 15) << 2, rq = t >> 4;
    #pragma unroll
    for (int p = 0; p < 4; ++p) {
        int r = p * 16 + rq;
        long long ib = (long long)(m0 + r) * N + n0 + c4;
        ushort4_t vh = *(const ushort4_t*)(ipH + ib);
        ushort4_t vl = *(const ushort4_t*)(ipL + ib);
        SH[r][c4+0]=vh[0]; SH[r][c4+1]=vh[1]; SH[r][c4+2]=vh[2]; SH[r][c4+3]=vh[3];
        SL[r][c4+0]=vl[0]; SL[r][c4+1]=vl[1]; SL[r][c4+2]=vl[2]; SL[r][c4+3]=vl[3];
    }
    __syncthreads();
    #pragma unroll
    for (int p = 0; p < 4; ++p) {
        int nr = p * 16 + rq;
        ushort4_t h, l;
        h[0]=SH[c4+0][nr]; h[1]=SH[c4+1][nr]; h[2]=SH[c4+2][nr]; h[3]=SH[c4+3][nr];
        l[0]=SL[c4+0][nr]; l[1]=SL[c4+1][nr]; l[2]=SL[c4+2][nr]; l[3]=SL[c4+3][nr];
        long long ob = (long long)(n0 + nr) * M + m0 + c4;
        *(ushort4_t*)(opH + ob) = h;
        *(ushort4_t*)(opL + ob) = l;
    }
}

// ---------------- helpers ----------------
__device__ inline float waveMax(float v) {
    #pragma unroll
    for (int o = 32; o; o >>= 1) v = fmaxf(v, __shfl_xor(v, o, 64));
    return v;
}
__device__ inline float waveSum(float v) {
    #pragma unroll
    for (int o = 32; o; o >>= 1) v += __shfl_xor(v, o, 64);
    return v;
}

// fp32 -> hi/lo bf16 planes (for weights)
__global__ __launch_bounds__(256) void conv_planes(
    const float* __restrict__ src, u16* __restrict__ h, u16* __restrict__ l, int n4)
{
    int i = blockIdx.x * 256 + threadIdx.x;
    if (i >= n4) return;
    float4 v = ((const float4*)src)[i];
    unsigned p0 = cvt_hl(v.x), p1 = cvt_hl(v.y), p2 = cvt_hl(v.z), p3 = cvt_hl(v.w);
    ushort4_t hv, lv;
    hv[0]=(u16)p0; hv[1]=(u16)p1; hv[2]=(u16)p2; hv[3]=(u16)p3;
    lv[0]=(u16)(p0>>16); lv[1]=(u16)(p1>>16); lv[2]=(u16)(p2>>16); lv[3]=(u16)(p3>>16);
    ((ushort4_t*)h)[i] = hv;
    ((ushort4_t*)l)[i] = lv;
}

// pAlpha[b,r,:] = softmax over l of masked pScoreT[b,r,:] -> hi/lo planes
__global__ __launch_bounds__(256) void softmax_LT(
    const float* __restrict__ pT, const int* __restrict__ mask,
    u16* __restrict__ outH, u16* __restrict__ outL)
{
    __shared__ float sm[4], ss[4];
    int zi = blockIdx.x;              // b*R + r
    int b = zi >> 8;
    const float* row = pT + (long long)zi * L_;
    const int* mk = mask + (long long)b * L_ * L_;   // row 0 of [L,L]
    float vals[8];
    float mx = -3.4e38f;
    #pragma unroll
    for (int i = 0; i < 8; ++i) {
        int l = threadIdx.x + i * 256;
        float v = row[l];
        if (mk[l] == 0) v = MASK_NEG;
        vals[i] = v; mx = fmaxf(mx, v);
    }
    int lane = threadIdx.x & 63, wid = threadIdx.x >> 6;
    mx = waveMax(mx);
    if (lane == 0) sm[wid] = mx;
    __syncthreads();
    mx = fmaxf(fmaxf(sm[0], sm[1]), fmaxf(sm[2], sm[3]));
    float sum = 0.0f;
    #pragma unroll
    for (int i = 0; i < 8; ++i) { float e = __expf(vals[i] - mx); vals[i] = e; sum += e; }
    sum = waveSum(sum);
    if (lane == 0) ss[wid] = sum;
    __syncthreads();
    sum = ss[0] + ss[1] + ss[2] + ss[3];
    float inv = 1.0f / sum;
    long long base = (long long)zi * L_;
    #pragma unroll
    for (int i = 0; i < 8; ++i) {
        unsigned p = cvt_hl(vals[i] * inv);
        outH[base + threadIdx.x + i * 256] = (u16)p;
        outL[base + threadIdx.x + i * 256] = (u16)(p >> 16);
    }
}

// pAlpha_[b,l,:] = softmax over r of masked pScore[b,l,:] -> hi/lo planes
__global__ __launch_bounds__(256) void softmax_R(
    const float* __restrict__ pScore, const int* __restrict__ mask,
    u16* __restrict__ outH, u16* __restrict__ outL)
{
    __shared__ float sm[4], ss[4];
    long long z = blockIdx.x;    // b*L + l
    int b = (int)(z >> 11), l = (int)(z & 2047);
    bool pad = (mask[(long long)b * L_ * L_ + l] == 0);
    float v = pScore[z * R_ + threadIdx.x];
    if (pad) v = MASK_NEG;
    int lane = threadIdx.x & 63, wid = threadIdx.x >> 6;
    float mx = waveMax(v);
    if (lane == 0) sm[wid] = mx;
    __syncthreads();
    mx = fmaxf(fmaxf(sm[0], sm[1]), fmaxf(sm[2], sm[3]));
    float e = __expf(v - mx);
    float sum = waveSum(e);
    if (lane == 0) ss[wid] = sum;
    __syncthreads();
    sum = ss[0] + ss[1] + ss[2] + ss[3];
    unsigned p = cvt_hl(e / sum);
    outH[z * R_ + threadIdx.x] = (u16)p;
    outL[z * R_ + threadIdx.x] = (u16)(p >> 16);
}

// alpha = softmax(scores,-1) -> planes; per-row offdiag sum -> offArr[row]
__global__ __launch_bounds__(256) void softmax_alpha(
    const float* __restrict__ scores, u16* __restrict__ aH, u16* __restrict__ aL,
    float* __restrict__ offArr)
{
    __shared__ float sm[4], ss[4], so[4];
    long long row = blockIdx.x;  // over B*H*R
    int r = (int)(row & 255);
    float v = scores[row * 256 + threadIdx.x];
    int lane = threadIdx.x & 63, wid = threadIdx.x >> 6;
    float mx = waveMax(v);
    if (lane == 0) sm[wid] = mx;
    __syncthreads();
    mx = fmaxf(fmaxf(sm[0], sm[1]), fmaxf(sm[2], sm[3]));
    float e = __expf(v - mx);
    float sum = waveSum(e);
    if (lane == 0) ss[wid] = sum;
    __syncthreads();
    sum = ss[0] + ss[1] + ss[2] + ss[3];
    float a = e / sum;
    unsigned p = cvt_hl(a);
    aH[row * 256 + threadIdx.x] = (u16)p;
    aL[row * 256 + threadIdx.x] = (u16)(p >> 16);
    float off = (threadIdx.x == r) ? 0.0f : a;
    off = waveSum(off);
    if (lane == 0) so[wid] = off;
    __syncthreads();
    if (threadIdx.x == 0) offArr[row] = so[0] + so[1] + so[2] + so[3];
}

__global__ __launch_bounds__(256) void finalize_loss(
    const float* __restrict__ addLossIn, const float* __restrict__ lossAcc,
    const float* __restrict__ offArr, float* __restrict__ out)
{
    __shared__ float red[4];
    float s = 0.0f;
    for (int i = threadIdx.x; i < B_ * H_ * R_; i += 256) s += offArr[i];
    int lane = threadIdx.x & 63, wid = threadIdx.x >> 6;
    s = waveSum(s);
    if (lane == 0) red[wid] = s;
    __syncthreads();
    if (threadIdx.x == 0) {
        float total = red[0] + red[1] + red[2] + red[3];
        out[0] = addLossIn[0]
               + lossAcc[0] * (1.0f / ((float)B_ * R_ * R_))
               + total      * (1.0f / ((float)B_ * H_ * R_ * R_))
               + lossAcc[2] * (1.0f / ((float)B_ * R_ * R_));
    }
}

// ---------------- launch ----------------
extern "C" void kernel_launch(void* const* d_in, const int* in_sizes, int n_in,
                              void* d_out, int out_size, void* d_ws, size_t ws_size,
                              hipStream_t stream)
{
    const float* qx = (const float*)d_in[0];
    const float* kx = (const float*)d_in[1];
    const float* vx = (const float*)d_in[2];
    const float* addLossIn = (const float*)d_in[3];
    const int* mask = (const int*)d_in[4];
    const float* Wp = (const float*)d_in[5];
    const float* WQ = (const float*)d_in[6];
    const float* WK = (const float*)d_in[7];
    const float* WV = (const float*)d_in[8];
    const float* WO = (const float*)d_in[9];

    float* zOut      = (float*)d_out;                             // [B,L,C]
    float* scoresOut = zOut + (long long)B_ * L_ * C_;            // [B,H,R,R]
    float* lossOut   = scoresOut + (long long)B_ * H_ * R_ * R_;  // [1]

    const long long SZ_BLR = (long long)B_ * L_ * R_;   // 4,194,304
    const long long SZ_BRC = (long long)B_ * R_ * C_;   // 1,048,576
    float* w = (float*)d_ws;
    u16* W16 = (u16*)d_ws;

    // ---- region X (first 2*SZ_BLR floats = 4*SZ_BLR u16 = 33.5MB), time-multiplexed ----
    // phase A: pScore fp32 [0..SZ_BLR), pScoreT fp32 [SZ_BLR..2SZ_BLR) (float idx)
    // phase B: pAT planes u16 [0..2SZ_BLR)
    // phase C: xT planes u16 [0..4SZ_BLR)
    // phase D: alpha u16 [0..2SZ_BLR); z1/z2/z2T u16 [2SZ_BLR..2SZ_BLR+6SZ_BRC);
    //          vpT u16 [2SZ_BLR+6SZ_BRC..4SZ_BLR)  (2SZ_BLR+8SZ_BRC == 4SZ_BLR exactly)
    float* pScore  = w;
    float* pScoreT = w + SZ_BLR;
    u16* pATH = W16;
    u16* pATL = W16 + SZ_BLR;
    u16* xTH  = W16;
    u16* xTL  = W16 + 2 * SZ_BLR;
    u16* alphaH = W16;
    u16* alphaL = W16 + (long long)B_ * H_ * R_ * R_;
    u16* z1H = W16 + 2 * SZ_BLR;
    u16* z1L = z1H + SZ_BRC;
    u16* z2H = z1H + 2 * SZ_BRC;
    u16* z2L = z1H + 3 * SZ_BRC;
    u16* z2TH = z1H + 4 * SZ_BRC;
    u16* z2TL = z1H + 5 * SZ_BRC;
    u16* vpTH = z1H + 6 * SZ_BRC;     // FIXED: was overlapping alpha planes
    u16* vpTL = z1H + 7 * SZ_BRC;

    // ---- persistent tail (starts at byte 4*SZ_BLR*2 = 33.5MB) ----
    u16* pAlphaH  = (u16*)(w + 2 * SZ_BLR);      // [B,R,L] planes
    u16* pAlphaL  = pAlphaH + SZ_BLR;
    u16* pAlpha_H = pAlphaH + 2 * SZ_BLR;        // [B,L,R] planes
    u16* pAlpha_L = pAlphaH + 3 * SZ_BLR;
    u16* qrH = pAlphaH + 4 * SZ_BLR;             // 12 planes of SZ_BRC
    u16* qrL = qrH + SZ_BRC;
    u16* krH = qrH + 2 * SZ_BRC;
    u16* krL = qrH + 3 * SZ_BRC;
    u16* vrH = qrH + 4 * SZ_BRC;
    u16* vrL = qrH + 5 * SZ_BRC;
    u16* qpH = qrH + 6 * SZ_BRC;
    u16* qpL = qrH + 7 * SZ_BRC;
    u16* kpH = qrH + 8 * SZ_BRC;
    u16* kpL = qrH + 9 * SZ_BRC;
    u16* vpH = qrH + 10 * SZ_BRC;
    u16* vpL = qrH + 11 * SZ_BRC;
    u16* WpH = qrH + 12 * SZ_BRC;
    u16* WpL = WpH + (long long)R_ * C_;
    u16* WQH = WpL + (long long)R_ * C_;
    u16* WQL = WQH + (long long)HD_ * C_;
    u16* WKH = WQL + (long long)HD_ * C_;
    u16* WKL = WKH + (long long)HD_ * C_;
    u16* WVH = WKL + (long long)HD_ * C_;
    u16* WVL = WVH + (long long)HD_ * C_;
    u16* WOH = WVL + (long long)HD_ * C_;
    u16* WOL = WOH + (long long)HD_ * C_;
    float* loss   = (float*)(WOL + (long long)HD_ * C_);
    float* offArr = loss + 16;                   // 16384 floats

    const Ptr3 N3{nullptr, nullptr, nullptr};
    auto P1 = [](const void* p) { return Ptr3{p, p, p}; };
    const long long llRL = (long long)R_ * L_, llLC = (long long)L_ * C_;
    const long long llRC = (long long)R_ * C_, llRHD = (long long)R_ * HD_;
    const long long llRR = (long long)R_ * R_, llHRR = (long long)H_ * R_ * R_;
    const long long llCL = (long long)C_ * L_;

    (void)hipMemsetAsync(loss, 0, 3 * sizeof(float), stream);

    // 0) weights -> planes
    conv_planes<<<(R_*C_/4 + 255)/256, 256, 0, stream>>>(Wp, WpH, WpL, R_*C_/4);
    conv_planes<<<(HD_*C_/4 + 255)/256, 256, 0, stream>>>(WQ, WQH, WQL, HD_*C_/4);
    conv_planes<<<(HD_*C_/4 + 255)/256, 256, 0, stream>>>(WK, WKH, WKL, HD_*C_/4);
    conv_planes<<<(HD_*C_/4 + 255)/256, 256, 0, stream>>>(WV, WVH, WVL, HD_*C_/4);
    conv_planes<<<(HD_*C_/4 + 255)/256, 256, 0, stream>>>(WO, WOH, WOL, HD_*C_/4);

    // 1) pScore = vx @ Wp^T : [16384,256], K=512
    gemm_pl<128, 2, 0, 0, false><<<dim3(2, 256, 1), 256, 0, stream>>>(
        P1(vx), N3, P1(WpH), P1(WpL), P1(pScore), N3,
        C_, C_, C_, R_, 1, 0, 0, 0, 0, 0, 0, 1.0f, nullptr);

    // 2) pScoreT = transpose(pScore) per batch: [L,R] -> [R,L]
    xpose_f32<<<dim3(R_/64, L_/64, B_), 256, 0, stream>>>(
        pScore, pScoreT, L_, R_, llRL, llRL);

    // 3) softmaxes -> planes
    softmax_LT<<<B_ * R_, 256, 0, stream>>>(pScoreT, mask, pAlphaH, pAlphaL);
    softmax_R<<<B_ * L_, 256, 0, stream>>>(pScore, mask, pAlpha_H, pAlpha_L);

    // 3b) pAT = transpose(pAlpha_) planes: [L,R] -> [R,L]  (into region X, pScore dead)
    xpose_u16p<<<dim3(R_/64, L_/64, B_), 256, 0, stream>>>(
        pAlpha_H, pAlpha_L, pATH, pATL, L_, R_, llRL, llRL);

    // 4) loss1: offdiag (pAlpha @ pAlpha^T)^2, K=2048
    gemm_pl<64, 0, 0, 1, false><<<dim3(4, 4, 8), 256, 0, stream>>>(
        P1(pAlphaH), P1(pAlphaL), P1(pAlphaH), P1(pAlphaL), N3, N3,
        L_, L_, L_, 0, 8, llRL, llRL, 0, 0, 0, 0, 1.0f, loss + 0);

    // 5) loss3: offdiag (pAT @ pAT^T)^2, K=2048
    gemm_pl<64, 0, 0, 1, false><<<dim3(4, 4, 8), 256, 0, stream>>>(
        P1(pATH), P1(pATL), P1(pATH), P1(pATL), N3, N3,
        L_, L_, L_, 0, 8, llRL, llRL, 0, 0, 0, 0, 1.0f, loss + 2);

    // 6) per member: xT = transpose(x) -> planes [C][L]; then {q,k,v}r = pAlpha @ x
    const float* xs[3]  = {qx, kx, vx};
    u16* outsH[3] = {qrH, krH, vrH};
    u16* outsL[3] = {qrL, krL, vrL};
    for (int m = 0; m < 3; ++m) {
        xpose_f32p<<<dim3(C_/64, L_/64, B_), 256, 0, stream>>>(
            xs[m], xTH, xTL, L_, C_, llLC, llCL);
        gemm_pl<64, 0, 0, 2, false><<<dim3(C_/64, R_/64, B_), 256, 0, stream>>>(
            P1(pAlphaH), P1(pAlphaL), P1(xTH), P1(xTL), P1(outsH[m]), P1(outsL[m]),
            L_, L_, L_, C_, 8, llRL, llCL, llRC, 0, 0, 0, 1.0f, nullptr);
    }

    // 7) projections: {qp,kp,vp} = {qr,kr,vr} @ {WQ,WK,WV}^T : [2048,512], K=512 (triple)
    gemm_pl<64, 0, 0, 2, true><<<dim3(8, 32, 3), 256, 0, stream>>>(
        Ptr3{qrH, krH, vrH}, Ptr3{qrL, krL, vrL},
        Ptr3{WQH, WKH, WVH}, Ptr3{WQL, WKL, WVL},
        Ptr3{qpH, kpH, vpH}, Ptr3{qpL, kpL, vpL},
        C_, C_, C_, HD_, 1, 0, 0, 0, 0, 0, 0, 1.0f, nullptr);

    // 7b) vpT = transpose(vp) planes per batch: [R,HD] -> [HD,R]
    xpose_u16p<<<dim3(HD_/64, R_/64, B_), 256, 0, stream>>>(
        vpH, vpL, vpTH, vpTL, R_, HD_, llRHD, llRHD);

    // 8) scores = qp_h @ kp_h^T / 8 : [256,256] x64, K=64
    gemm_pl<64, 0, 0, 0, false><<<dim3(4, 4, 64), 256, 0, stream>>>(
        P1(qpH), P1(qpL), P1(kpH), P1(kpL), P1(scoresOut), N3,
        DK_, HD_, HD_, R_, 8, 64, 64, llRR, llRHD, llRHD, llHRR, 0.125f, nullptr);

    // 9) alpha = softmax(scores) -> planes + offArr
    softmax_alpha<<<B_ * H_ * R_, 256, 0, stream>>>(scoresOut, alphaH, alphaL, offArr);

    // 10) z1 = alpha @ vp_h : [256,64] x64, K=256 (B = vpT slice, BMODE0)
    gemm_pl<64, 0, 0, 2, false><<<dim3(1, 4, 64), 256, 0, stream>>>(
        P1(alphaH), P1(alphaL), P1(vpTH), P1(vpTL), P1(z1H), P1(z1L),
        R_, R_, R_, HD_, 8, llRR, (long long)64 * R_, 64, llHRR, llRHD, llRHD, 1.0f, nullptr);

    // 11) z2 = z1 @ WO^T : [2048,512], K=512
    gemm_pl<64, 0, 0, 2, false><<<dim3(8, 32, 1), 256, 0, stream>>>(
        P1(z1H), P1(z1L), P1(WOH), P1(WOL), P1(z2H), P1(z2L),
        HD_, HD_, HD_, C_, 1, 0, 0, 0, 0, 0, 0, 1.0f, nullptr);

    // 11b) z2T = transpose(z2) planes per batch: [R,C] -> [C,R]
    xpose_u16p<<<dim3(C_/64, R_/64, B_), 256, 0, stream>>>(
        z2H, z2L, z2TH, z2TL, R_, C_, llRC, llRC);

    // 12) z = pAlpha_ @ z2 : [2048,512] x8, K=256 (B = z2T, BMODE0)
    gemm_pl<64, 0, 0, 0, false><<<dim3(8, 32, 8), 256, 0, stream>>>(
        P1(pAlpha_H), P1(pAlpha_L), P1(z2TH), P1(z2TL), P1(zOut), N3,
        R_, R_, R_, C_, 8, llRL, llRC, llLC, 0, 0, 0, 1.0f, nullptr);

    // 13) addLoss
    finalize_loss<<<1, 256, 0, stream>>>(addLossIn, loss, offArr, lossOut);
}

// Round 9
// 415.216 us; speedup vs baseline: 1.2087x; 1.2087x over previous
//
#include <hip/hip_runtime.h>

#define B_  8
#define L_  2048
#define C_  512
#define R_  256
#define H_  8
#define DK_ 64
#define HD_ 512
#define MASK_NEG (-32767.0f)

typedef __attribute__((ext_vector_type(8))) short short8;
typedef __attribute__((ext_vector_type(8))) unsigned short ushort8;
typedef __attribute__((ext_vector_type(4))) unsigned short ushort4_t;
typedef __attribute__((ext_vector_type(4))) float f32x4;
typedef unsigned short u16;

__device__ inline u16 bf16_rne(float x) {
    unsigned u = __float_as_uint(x);
    return (u16)((u + 0x7FFFu + ((u >> 16) & 1u)) >> 16);
}
// hi bf16 in low 16 bits, lo bf16 in high 16 bits
__device__ inline unsigned cvt_hl(float x) {
    u16 hh = bf16_rne(x);
    float hf = __uint_as_float(((unsigned)hh) << 16);
    u16 ll = bf16_rne(x - hf);
    return (unsigned)hh | ((unsigned)ll << 16);
}

struct Ptr3 { const void* p0; const void* p1; const void* p2; };

// ---------------- MFMA plane GEMM ----------------
// C = scale * A @ B via 3-term split MFMA (Ah@Bh + Ah@Bl + Al@Bh).
// AMODE: 0 = bf16 planes [M][K]; 2 = fp32 [M][K] (cvt on stage)
// BMODE: 0 = bf16 planes [N][K]
// EPI:   0 = store fp32 C*scale; 2 = store hi/lo planes
// Batch: z -> zb=z/divz, zh=z%divz. TRIPLE: zb picks pointer from Ptr3 (offset zh*sh);
//        else offsets zb*sb + zh*sh.
template<int BN, int AMODE, int BMODE, int EPI, bool TRIPLE>
__global__ __launch_bounds__(256) void gemm_pl(
    Ptr3 aH, Ptr3 aL, Ptr3 bH, Ptr3 bL, Ptr3 cH, Ptr3 cL,
    int K, int lda, int ldb, int ldc, int divz,
    long long ash, long long bsh, long long csh,
    long long asb, long long bsb, long long csb,
    float scale)
{
    constexpr int NF = BN / 32;
    __shared__ u16 Ahs[64][40], Als[64][40];
    __shared__ u16 Bhs[BN][40], Bls[BN][40];

    const int z  = blockIdx.z;
    const int zb = z / divz, zh = z - zb * divz;
    const void* avH = TRIPLE ? (zb == 0 ? aH.p0 : zb == 1 ? aH.p1 : aH.p2) : aH.p0;
    const void* avL = TRIPLE ? (zb == 0 ? aL.p0 : zb == 1 ? aL.p1 : aL.p2) : aL.p0;
    const void* bvH = TRIPLE ? (zb == 0 ? bH.p0 : zb == 1 ? bH.p1 : bH.p2) : bH.p0;
    const void* bvL = TRIPLE ? (zb == 0 ? bL.p0 : zb == 1 ? bL.p1 : bL.p2) : bL.p0;
    void* cvH = (void*)(TRIPLE ? (zb == 0 ? cH.p0 : zb == 1 ? cH.p1 : cH.p2) : cH.p0);
    void* cvL = (void*)(TRIPLE ? (zb == 0 ? cL.p0 : zb == 1 ? cL.p1 : cL.p2) : cL.p0);
    const long long ao = (TRIPLE ? 0 : (long long)zb * asb) + (long long)zh * ash;
    const long long bo = (TRIPLE ? 0 : (long long)zb * bsb) + (long long)zh * bsh;
    const long long co = (TRIPLE ? 0 : (long long)zb * csb) + (long long)zh * csh;

    const u16*   AHg = (const u16*)avH + ao;
    const u16*   ALg = (const u16*)avL + ao;
    const float* Afg = (const float*)avH + ao;
    const u16*   BHg = (const u16*)bvH + bo;
    const u16*   BLg = (const u16*)bvL + bo;
    float* Cf  = (float*)cvH + co;
    u16*   CHg = (u16*)cvH + co;
    u16*   CLg = (u16*)cvL + co;

    const int m0 = blockIdx.y * 64, n0 = blockIdx.x * BN;
    const int tid = threadIdx.x;
    const int lane = tid & 63, w = tid >> 6;
    const int wrow = (w >> 1) * 32, wcol = (w & 1) * (BN / 2);
    const int l15 = lane & 15, lg = lane >> 4;

    f32x4 zero = {0.f, 0.f, 0.f, 0.f};
    f32x4 acc[2][NF];
    #pragma unroll
    for (int mf = 0; mf < 2; ++mf)
        #pragma unroll
        for (int nf = 0; nf < NF; ++nf) acc[mf][nf] = zero;

    for (int k0 = 0; k0 < K; k0 += 32) {
        // ---- stage A (64 x 32) ----
        if (AMODE == 0) {
            int row = tid >> 2, kc = (tid & 3) << 3;
            long long off = (long long)(m0 + row) * lda + (k0 + kc);
            *(ushort8*)&Ahs[row][kc] = *(const ushort8*)(AHg + off);
            *(ushort8*)&Als[row][kc] = *(const ushort8*)(ALg + off);
        } else { // AMODE == 2: fp32 [M][K]
            int row = tid >> 2, kc = (tid & 3) << 3;
            const float* s = Afg + (long long)(m0 + row) * lda + (k0 + kc);
            float4 v0 = *(const float4*)s, v1 = *(const float4*)(s + 4);
            unsigned p0 = cvt_hl(v0.x), p1 = cvt_hl(v0.y), p2 = cvt_hl(v0.z), p3 = cvt_hl(v0.w);
            unsigned p4 = cvt_hl(v1.x), p5 = cvt_hl(v1.y), p6 = cvt_hl(v1.z), p7 = cvt_hl(v1.w);
            ushort8 h, l;
            h[0]=(u16)p0; h[1]=(u16)p1; h[2]=(u16)p2; h[3]=(u16)p3;
            h[4]=(u16)p4; h[5]=(u16)p5; h[6]=(u16)p6; h[7]=(u16)p7;
            l[0]=(u16)(p0>>16); l[1]=(u16)(p1>>16); l[2]=(u16)(p2>>16); l[3]=(u16)(p3>>16);
            l[4]=(u16)(p4>>16); l[5]=(u16)(p5>>16); l[6]=(u16)(p6>>16); l[7]=(u16)(p7>>16);
            *(ushort8*)&Ahs[row][kc] = h;
            *(ushort8*)&Als[row][kc] = l;
        }
        // ---- stage B (BN x 32), planes [N][K] ----
        #pragma unroll
        for (int t = tid; t < BN * 4; t += 256) {
            int row = t >> 2, kc = (t & 3) << 3;
            long long off = (long long)(n0 + row) * ldb + (k0 + kc);
            *(ushort8*)&Bhs[row][kc] = *(const ushort8*)(BHg + off);
            *(ushort8*)&Bls[row][kc] = *(const ushort8*)(BLg + off);
        }
        __syncthreads();

        short8 a_h[2], a_l[2];
        a_h[0] = *(const short8*)&Ahs[wrow +      l15][lg * 8];
        a_h[1] = *(const short8*)&Ahs[wrow + 16 + l15][lg * 8];
        a_l[0] = *(const short8*)&Als[wrow +      l15][lg * 8];
        a_l[1] = *(const short8*)&Als[wrow + 16 + l15][lg * 8];
        #pragma unroll
        for (int nf = 0; nf < NF; ++nf) {
            short8 b_h = *(const short8*)&Bhs[wcol + nf * 16 + l15][lg * 8];
            short8 b_l = *(const short8*)&Bls[wcol + nf * 16 + l15][lg * 8];
            #pragma unroll
            for (int mf = 0; mf < 2; ++mf) {
                acc[mf][nf] = __builtin_amdgcn_mfma_f32_16x16x32_bf16(a_h[mf], b_h, acc[mf][nf], 0, 0, 0);
                acc[mf][nf] = __builtin_amdgcn_mfma_f32_16x16x32_bf16(a_h[mf], b_l, acc[mf][nf], 0, 0, 0);
                acc[mf][nf] = __builtin_amdgcn_mfma_f32_16x16x32_bf16(a_l[mf], b_h, acc[mf][nf], 0, 0, 0);
            }
        }
        __syncthreads();
    }

    if (EPI == 0) {
        #pragma unroll
        for (int mf = 0; mf < 2; ++mf)
            #pragma unroll
            for (int nf = 0; nf < NF; ++nf) {
                int row = m0 + wrow + mf * 16 + lg * 4;
                int col = n0 + wcol + nf * 16 + l15;
                #pragma unroll
                for (int j = 0; j < 4; ++j)
                    Cf[(long long)(row + j) * ldc + col] = acc[mf][nf][j] * scale;
            }
    } else {
        #pragma unroll
        for (int mf = 0; mf < 2; ++mf)
            #pragma unroll
            for (int nf = 0; nf < NF; ++nf) {
                int row = m0 + wrow + mf * 16 + lg * 4;
                int col = n0 + wcol + nf * 16 + l15;
                #pragma unroll
                for (int j = 0; j < 4; ++j) {
                    unsigned p = cvt_hl(acc[mf][nf][j] * scale);
                    CHg[(long long)(row + j) * ldc + col] = (u16)p;
                    CLg[(long long)(row + j) * ldc + col] = (u16)(p >> 16);
                }
            }
    }
}

// ---------------- split-K loss reduce ----------------
// G partials: [KS][B][R][R] fp32. loss += sum over b, i!=j of (sum_ks Gpart)^2
#define KS_ 8
__global__ __launch_bounds__(256) void loss_reduce(
    const float* __restrict__ G, float* __restrict__ lossDst)
{
    __shared__ float red[4];
    const long long N = (long long)B_ * R_ * R_;
    float s = 0.0f;
    for (long long idx = (long long)blockIdx.x * 256 + threadIdx.x; idx < N;
         idx += (long long)gridDim.x * 256) {
        float g = 0.0f;
        #pragma unroll
        for (int ks = 0; ks < KS_; ++ks) g += G[(long long)ks * N + idx];
        int e = (int)(idx & (long long)(R_ * R_ - 1));
        int row = e >> 8, col = e & 255;
        if (row != col) s += g * g;
    }
    #pragma unroll
    for (int o = 32; o; o >>= 1) s += __shfl_down(s, o, 64);
    int lane = threadIdx.x & 63, wid = threadIdx.x >> 6;
    if (lane == 0) red[wid] = s;
    __syncthreads();
    if (threadIdx.x == 0) atomicAdd(lossDst, red[0] + red[1] + red[2] + red[3]);
}

// ---------------- transpose kernels ----------------
// fp32 [M][N] -> fp32 [N][M], batched over z
__global__ __launch_bounds__(256) void xpose_f32(
    const float* __restrict__ in, float* __restrict__ out,
    int M, int N, long long ibs, long long obs)
{
    __shared__ float S[64][65];
    const float* ip = in + (long long)blockIdx.z * ibs;
    float* op = out + (long long)blockIdx.z * obs;
    int n0 = blockIdx.x * 64, m0 = blockIdx.y * 64;
    int t = threadIdx.x;
    int c4 = (t & 15) << 2, rq = t >> 4;
    #pragma unroll
    for (int p = 0; p < 4; ++p) {
        int r = p * 16 + rq;
        float4 v = *(const float4*)(ip + (long long)(m0 + r) * N + n0 + c4);
        S[r][c4+0]=v.x; S[r][c4+1]=v.y; S[r][c4+2]=v.z; S[r][c4+3]=v.w;
    }
    __syncthreads();
    #pragma unroll
    for (int p = 0; p < 4; ++p) {
        int nr = p * 16 + rq;
        float4 o;
        o.x = S[c4+0][nr]; o.y = S[c4+1][nr]; o.z = S[c4+2][nr]; o.w = S[c4+3][nr];
        *(float4*)(op + (long long)(n0 + nr) * M + m0 + c4) = o;
    }
}

// fp32 [M][N] -> bf16 hi/lo planes [N][M], triple-batched: z -> (member, batch)
__global__ __launch_bounds__(256) void xpose_f32p3(
    Ptr3 src, Ptr3 dstH, Ptr3 dstL,
    int M, int N, long long ibs, long long obs, int divz)
{
    __shared__ float S[64][65];
    int z = blockIdx.z;
    int m = z / divz, b = z - m * divz;
    const float* ip = (const float*)(m == 0 ? src.p0 : m == 1 ? src.p1 : src.p2)
                      + (long long)b * ibs;
    u16* opH = (u16*)(m == 0 ? dstH.p0 : m == 1 ? dstH.p1 : dstH.p2) + (long long)b * obs;
    u16* opL = (u16*)(m == 0 ? dstL.p0 : m == 1 ? dstL.p1 : dstL.p2) + (long long)b * obs;
    int n0 = blockIdx.x * 64, m0 = blockIdx.y * 64;
    int t = threadIdx.x;
    int c4 = (t & 15) << 2, rq = t >> 4;
    #pragma unroll
    for (int p = 0; p < 4; ++p) {
        int r = p * 16 + rq;
        float4 v = *(const float4*)(ip + (long long)(m0 + r) * N + n0 + c4);
        S[r][c4+0]=v.x; S[r][c4+1]=v.y; S[r][c4+2]=v.z; S[r][c4+3]=v.w;
    }
    __syncthreads();
    #pragma unroll
    for (int p = 0; p < 4; ++p) {
        int nr = p * 16 + rq;
        unsigned q0 = cvt_hl(S[c4+0][nr]), q1 = cvt_hl(S[c4+1][nr]);
        unsigned q2 = cvt_hl(S[c4+2][nr]), q3 = cvt_hl(S[c4+3][nr]);
        ushort4_t h, l;
        h[0]=(u16)q0; h[1]=(u16)q1; h[2]=(u16)q2; h[3]=(u16)q3;
        l[0]=(u16)(q0>>16); l[1]=(u16)(q1>>16); l[2]=(u16)(q2>>16); l[3]=(u16)(q3>>16);
        long long ob = (long long)(n0 + nr) * M + m0 + c4;
        *(ushort4_t*)(opH + ob) = h;
        *(ushort4_t*)(opL + ob) = l;
    }
}

// u16 planes [M][N] -> planes [N][M], batched over z
__global__ __launch_bounds__(256) void xpose_u16p(
    const u16* __restrict__ inH, const u16* __restrict__ inL,
    u16* __restrict__ outH, u16* __restrict__ outL,
    int M, int N, long long ibs, long long obs)
{
    __shared__ u16 SH[64][66], SL[64][66];
    const u16* ipH = inH + (long long)blockIdx.z * ibs;
    const u16* ipL = inL + (long long)blockIdx.z * ibs;
    u16* opH = outH + (long long)blockIdx.z * obs;
    u16* opL = outL + (long long)blockIdx.z * obs;
    int n0 = blockIdx.x * 64, m0 = blockIdx.y * 64;
    int t = threadIdx.x;
    int c4 = (t & 15) << 2, rq = t >> 4;
    #pragma unroll
    for (int p = 0; p < 4; ++p) {
        int r = p * 16 + rq;
        long long ib = (long long)(m0 + r) * N + n0 + c4;
        ushort4_t vh = *(const ushort4_t*)(ipH + ib);
        ushort4_t vl = *(const ushort4_t*)(ipL + ib);
        SH[r][c4+0]=vh[0]; SH[r][c4+1]=vh[1]; SH[r][c4+2]=vh[2]; SH[r][c4+3]=vh[3];
        SL[r][c4+0]=vl[0]; SL[r][c4+1]=vl[1]; SL[r][c4+2]=vl[2]; SL[r][c4+3]=vl[3];
    }
    __syncthreads();
    #pragma unroll
    for (int p = 0; p < 4; ++p) {
        int nr = p * 16 + rq;
        ushort4_t h, l;
        h[0]=SH[c4+0][nr]; h[1]=SH[c4+1][nr]; h[2]=SH[c4+2][nr]; h[3]=SH[c4+3][nr];
        l[0]=SL[c4+0][nr]; l[1]=SL[c4+1][nr]; l[2]=SL[c4+2][nr]; l[3]=SL[c4+3][nr];
        long long ob = (long long)(n0 + nr) * M + m0 + c4;
        *(ushort4_t*)(opH + ob) = h;
        *(ushort4_t*)(opL + ob) = l;
    }
}

// ---------------- helpers ----------------
__device__ inline float waveMax(float v) {
    #pragma unroll
    for (int o = 32; o; o >>= 1) v = fmaxf(v, __shfl_xor(v, o, 64));
    return v;
}
__device__ inline float waveSum(float v) {
    #pragma unroll
    for (int o = 32; o; o >>= 1) v += __shfl_xor(v, o, 64);
    return v;
}

// fp32 -> hi/lo bf16 planes (for weights)
__global__ __launch_bounds__(256) void conv_planes(
    const float* __restrict__ src, u16* __restrict__ h, u16* __restrict__ l, int n4)
{
    int i = blockIdx.x * 256 + threadIdx.x;
    if (i >= n4) return;
    float4 v = ((const float4*)src)[i];
    unsigned p0 = cvt_hl(v.x), p1 = cvt_hl(v.y), p2 = cvt_hl(v.z), p3 = cvt_hl(v.w);
    ushort4_t hv, lv;
    hv[0]=(u16)p0; hv[1]=(u16)p1; hv[2]=(u16)p2; hv[3]=(u16)p3;
    lv[0]=(u16)(p0>>16); lv[1]=(u16)(p1>>16); lv[2]=(u16)(p2>>16); lv[3]=(u16)(p3>>16);
    ((ushort4_t*)h)[i] = hv;
    ((ushort4_t*)l)[i] = lv;
}

// pAlpha[b,r,:] = softmax over l of masked pScoreT[b,r,:] -> hi/lo planes
__global__ __launch_bounds__(256) void softmax_LT(
    const float* __restrict__ pT, const int* __restrict__ mask,
    u16* __restrict__ outH, u16* __restrict__ outL)
{
    __shared__ float sm[4], ss[4];
    int zi = blockIdx.x;              // b*R + r
    int b = zi >> 8;
    const float* row = pT + (long long)zi * L_;
    const int* mk = mask + (long long)b * L_ * L_;   // row 0 of [L,L]
    float vals[8];
    float mx = -3.4e38f;
    #pragma unroll
    for (int i = 0; i < 8; ++i) {
        int l = threadIdx.x + i * 256;
        float v = row[l];
        if (mk[l] == 0) v = MASK_NEG;
        vals[i] = v; mx = fmaxf(mx, v);
    }
    int lane = threadIdx.x & 63, wid = threadIdx.x >> 6;
    mx = waveMax(mx);
    if (lane == 0) sm[wid] = mx;
    __syncthreads();
    mx = fmaxf(fmaxf(sm[0], sm[1]), fmaxf(sm[2], sm[3]));
    float sum = 0.0f;
    #pragma unroll
    for (int i = 0; i < 8; ++i) { float e = __expf(vals[i] - mx); vals[i] = e; sum += e; }
    sum = waveSum(sum);
    if (lane == 0) ss[wid] = sum;
    __syncthreads();
    sum = ss[0] + ss[1] + ss[2] + ss[3];
    float inv = 1.0f / sum;
    long long base = (long long)zi * L_;
    #pragma unroll
    for (int i = 0; i < 8; ++i) {
        unsigned p = cvt_hl(vals[i] * inv);
        outH[base + threadIdx.x + i * 256] = (u16)p;
        outL[base + threadIdx.x + i * 256] = (u16)(p >> 16);
    }
}

// pAlpha_[b,l,:] = softmax over r of masked pScore[b,l,:] -> hi/lo planes
__global__ __launch_bounds__(256) void softmax_R(
    const float* __restrict__ pScore, const int* __restrict__ mask,
    u16* __restrict__ outH, u16* __restrict__ outL)
{
    __shared__ float sm[4], ss[4];
    long long z = blockIdx.x;    // b*L + l
    int b = (int)(z >> 11), l = (int)(z & 2047);
    bool pad = (mask[(long long)b * L_ * L_ + l] == 0);
    float v = pScore[z * R_ + threadIdx.x];
    if (pad) v = MASK_NEG;
    int lane = threadIdx.x & 63, wid = threadIdx.x >> 6;
    float mx = waveMax(v);
    if (lane == 0) sm[wid] = mx;
    __syncthreads();
    mx = fmaxf(fmaxf(sm[0], sm[1]), fmaxf(sm[2], sm[3]));
    float e = __expf(v - mx);
    float sum = waveSum(e);
    if (lane == 0) ss[wid] = sum;
    __syncthreads();
    sum = ss[0] + ss[1] + ss[2] + ss[3];
    unsigned p = cvt_hl(e / sum);
    outH[z * R_ + threadIdx.x] = (u16)p;
    outL[z * R_ + threadIdx.x] = (u16)(p >> 16);
}

// alpha = softmax(scores,-1) -> planes; per-row offdiag sum -> offArr[row]
__global__ __launch_bounds__(256) void softmax_alpha(
    const float* __restrict__ scores, u16* __restrict__ aH, u16* __restrict__ aL,
    float* __restrict__ offArr)
{
    __shared__ float sm[4], ss[4], so[4];
    long long row = blockIdx.x;  // over B*H*R
    int r = (int)(row & 255);
    float v = scores[row * 256 + threadIdx.x];
    int lane = threadIdx.x & 63, wid = threadIdx.x >> 6;
    float mx = waveMax(v);
    if (lane == 0) sm[wid] = mx;
    __syncthreads();
    mx = fmaxf(fmaxf(sm[0], sm[1]), fmaxf(sm[2], sm[3]));
    float e = __expf(v - mx);
    float sum = waveSum(e);
    if (lane == 0) ss[wid] = sum;
    __syncthreads();
    sum = ss[0] + ss[1] + ss[2] + ss[3];
    float a = e / sum;
    unsigned p = cvt_hl(a);
    aH[row * 256 + threadIdx.x] = (u16)p;
    aL[row * 256 + threadIdx.x] = (u16)(p >> 16);
    float off = (threadIdx.x == r) ? 0.0f : a;
    off = waveSum(off);
    if (lane == 0) so[wid] = off;
    __syncthreads();
    if (threadIdx.x == 0) offArr[row] = so[0] + so[1] + so[2] + so[3];
}

__global__ __launch_bounds__(256) void finalize_loss(
    const float* __restrict__ addLossIn, const float* __restrict__ lossAcc,
    const float* __restrict__ offArr, float* __restrict__ out)
{
    __shared__ float red[4];
    float s = 0.0f;
    for (int i = threadIdx.x; i < B_ * H_ * R_; i += 256) s += offArr[i];
    int lane = threadIdx.x & 63, wid = threadIdx.x >> 6;
    s = waveSum(s);
    if (lane == 0) red[wid] = s;
    __syncthreads();
    if (threadIdx.x == 0) {
        float total = red[0] + red[1] + red[2] + red[3];
        out[0] = addLossIn[0]
               + lossAcc[0] * (1.0f / ((float)B_ * R_ * R_))
               + total      * (1.0f / ((float)B_ * H_ * R_ * R_))
               + lossAcc[2] * (1.0f / ((float)B_ * R_ * R_));
    }
}

// ---------------- launch ----------------
extern "C" void kernel_launch(void* const* d_in, const int* in_sizes, int n_in,
                              void* d_out, int out_size, void* d_ws, size_t ws_size,
                              hipStream_t stream)
{
    const float* qx = (const float*)d_in[0];
    const float* kx = (const float*)d_in[1];
    const float* vx = (const float*)d_in[2];
    const float* addLossIn = (const float*)d_in[3];
    const int* mask = (const int*)d_in[4];
    const float* Wp = (const float*)d_in[5];
    const float* WQ = (const float*)d_in[6];
    const float* WK = (const float*)d_in[7];
    const float* WV = (const float*)d_in[8];
    const float* WO = (const float*)d_in[9];

    float* zOut      = (float*)d_out;                             // [B,L,C]
    float* scoresOut = zOut + (long long)B_ * L_ * C_;            // [B,H,R,R]
    float* lossOut   = scoresOut + (long long)B_ * H_ * R_ * R_;  // [1]

    const long long S = (long long)B_ * L_ * R_;    // 4,194,304
    const long long T = (long long)B_ * R_ * C_;    // 1,048,576
    u16* cur = (u16*)d_ws;
    auto takeU = [&](long long n) { u16* p = cur; cur += n; return p; };
    auto takeF = [&](long long n) { float* p = (float*)cur; cur += 2 * n; return p; };

    // ---- flat layout, no overlays (~265MB of 512MB ws) ----
    float* pScore   = takeF(S);          // [B,L,R]
    float* pScoreT  = takeF(S);          // [B,R,L]
    u16* pAlphaH  = takeU(S);            // [B,R,L]
    u16* pAlphaL  = takeU(S);
    u16* pAlpha_H = takeU(S);            // [B,L,R]
    u16* pAlpha_L = takeU(S);
    u16* pATH     = takeU(S);            // [B,R,L]
    u16* pATL     = takeU(S);
    u16* xTH0 = takeU(2*S); u16* xTL0 = takeU(2*S);   // [B,C,L] = 2S elems per plane!
    u16* xTH1 = takeU(2*S); u16* xTL1 = takeU(2*S);
    u16* xTH2 = takeU(2*S); u16* xTL2 = takeU(2*S);
    float* Gpart  = takeF((long long)KS_ * B_ * R_ * R_);  // split-K partials
    u16* qrH = takeU(T); u16* qrL = takeU(T);
    u16* krH = takeU(T); u16* krL = takeU(T);
    u16* vrH = takeU(T); u16* vrL = takeU(T);
    u16* qpH = takeU(T); u16* qpL = takeU(T);
    u16* kpH = takeU(T); u16* kpL = takeU(T);
    u16* vpH = takeU(T); u16* vpL = takeU(T);
    u16* vpTH = takeU(T); u16* vpTL = takeU(T);
    u16* z1H = takeU(T); u16* z1L = takeU(T);
    u16* z2H = takeU(T); u16* z2L = takeU(T);
    u16* z2TH = takeU(T); u16* z2TL = takeU(T);
    u16* alphaH = takeU(S); u16* alphaL = takeU(S);   // [B,H,R,R] = S elems
    u16* WpH = takeU((long long)R_ * C_); u16* WpL = takeU((long long)R_ * C_);
    u16* WQH = takeU((long long)HD_ * C_); u16* WQL = takeU((long long)HD_ * C_);
    u16* WKH = takeU((long long)HD_ * C_); u16* WKL = takeU((long long)HD_ * C_);
    u16* WVH = takeU((long long)HD_ * C_); u16* WVL = takeU((long long)HD_ * C_);
    u16* WOH = takeU((long long)HD_ * C_); u16* WOL = takeU((long long)HD_ * C_);
    float* loss   = takeF(16);
    float* offArr = takeF(B_ * H_ * R_);

    const Ptr3 N3{nullptr, nullptr, nullptr};
    auto P1 = [](const void* p) { return Ptr3{p, p, p}; };
    const long long llRL = (long long)R_ * L_, llLC = (long long)L_ * C_;
    const long long llRC = (long long)R_ * C_, llRHD = (long long)R_ * HD_;
    const long long llRR = (long long)R_ * R_, llHRR = (long long)H_ * R_ * R_;
    const long long llCL = (long long)C_ * L_;

    (void)hipMemsetAsync(loss, 0, 3 * sizeof(float), stream);

    // 0) weights -> planes
    conv_planes<<<(R_*C_/4 + 255)/256, 256, 0, stream>>>(Wp, WpH, WpL, R_*C_/4);
    conv_planes<<<(HD_*C_/4 + 255)/256, 256, 0, stream>>>(WQ, WQH, WQL, HD_*C_/4);
    conv_planes<<<(HD_*C_/4 + 255)/256, 256, 0, stream>>>(WK, WKH, WKL, HD_*C_/4);
    conv_planes<<<(HD_*C_/4 + 255)/256, 256, 0, stream>>>(WV, WVH, WVL, HD_*C_/4);
    conv_planes<<<(HD_*C_/4 + 255)/256, 256, 0, stream>>>(WO, WOH, WOL, HD_*C_/4);

    // 1) pScore = vx @ Wp^T : [16384,256], K=512
    gemm_pl<128, 2, 0, 0, false><<<dim3(2, 256, 1), 256, 0, stream>>>(
        P1(vx), N3, P1(WpH), P1(WpL), P1(pScore), N3,
        C_, C_, C_, R_, 1, 0, 0, 0, 0, 0, 0, 1.0f);

    // 2) pScoreT = transpose(pScore) per batch
    xpose_f32<<<dim3(R_/64, L_/64, B_), 256, 0, stream>>>(
        pScore, pScoreT, L_, R_, llRL, llRL);

    // 3) softmaxes -> planes
    softmax_LT<<<B_ * R_, 256, 0, stream>>>(pScoreT, mask, pAlphaH, pAlphaL);
    softmax_R<<<B_ * L_, 256, 0, stream>>>(pScore, mask, pAlpha_H, pAlpha_L);

    // 3b) pAT = transpose(pAlpha_) planes: [L,R] -> [R,L]
    xpose_u16p<<<dim3(R_/64, L_/64, B_), 256, 0, stream>>>(
        pAlpha_H, pAlpha_L, pATH, pATL, L_, R_, llRL, llRL);

    // 4) loss1: split-K Gram. Gpart[ks][b] = pAlpha @ pAlpha^T over K-chunk ks
    gemm_pl<64, 0, 0, 0, false><<<dim3(4, 4, KS_ * B_), 256, 0, stream>>>(
        P1(pAlphaH), P1(pAlphaL), P1(pAlphaH), P1(pAlphaL), P1(Gpart), N3,
        L_ / KS_, L_, L_, R_, B_,
        llRL, llRL, llRR,
        L_ / KS_, L_ / KS_, (long long)B_ * llRR, 1.0f);
    loss_reduce<<<64, 256, 0, stream>>>(Gpart, loss + 0);

    // 5) loss3: split-K Gram of pAT
    gemm_pl<64, 0, 0, 0, false><<<dim3(4, 4, KS_ * B_), 256, 0, stream>>>(
        P1(pATH), P1(pATL), P1(pATH), P1(pATL), P1(Gpart), N3,
        L_ / KS_, L_, L_, R_, B_,
        llRL, llRL, llRR,
        L_ / KS_, L_ / KS_, (long long)B_ * llRR, 1.0f);
    loss_reduce<<<64, 256, 0, stream>>>(Gpart, loss + 2);

    // 6) xT = transpose all three inputs -> planes [C][L] (one launch, z=24)
    xpose_f32p3<<<dim3(C_/64, L_/64, 3 * B_), 256, 0, stream>>>(
        Ptr3{qx, kx, vx}, Ptr3{xTH0, xTH1, xTH2}, Ptr3{xTL0, xTL1, xTL2},
        L_, C_, llLC, llCL, B_);

    // 6b) {q,k,v}r = pAlpha @ x : triple-fused, z=24, 768 blocks
    gemm_pl<64, 0, 0, 2, true><<<dim3(C_/64, R_/64, 3 * B_), 256, 0, stream>>>(
        P1(pAlphaH), P1(pAlphaL),
        Ptr3{xTH0, xTH1, xTH2}, Ptr3{xTL0, xTL1, xTL2},
        Ptr3{qrH, krH, vrH}, Ptr3{qrL, krL, vrL},
        L_, L_, L_, C_, B_, llRL, llCL, llRC, 0, 0, 0, 1.0f);

    // 7) projections: {qp,kp,vp} = {qr,kr,vr} @ {WQ,WK,WV}^T : [2048,512], K=512 (triple)
    gemm_pl<64, 0, 0, 2, true><<<dim3(8, 32, 3), 256, 0, stream>>>(
        Ptr3{qrH, krH, vrH}, Ptr3{qrL, krL, vrL},
        Ptr3{WQH, WKH, WVH}, Ptr3{WQL, WKL, WVL},
        Ptr3{qpH, kpH, vpH}, Ptr3{qpL, kpL, vpL},
        C_, C_, C_, HD_, 1, 0, 0, 0, 0, 0, 0, 1.0f);

    // 7b) vpT = transpose(vp) planes per batch: [R,HD] -> [HD,R]
    xpose_u16p<<<dim3(HD_/64, R_/64, B_), 256, 0, stream>>>(
        vpH, vpL, vpTH, vpTL, R_, HD_, llRHD, llRHD);

    // 8) scores = qp_h @ kp_h^T / 8 : [256,256] x64, K=64
    gemm_pl<64, 0, 0, 0, false><<<dim3(4, 4, 64), 256, 0, stream>>>(
        P1(qpH), P1(qpL), P1(kpH), P1(kpL), P1(scoresOut), N3,
        DK_, HD_, HD_, R_, 8, 64, 64, llRR, llRHD, llRHD, llHRR, 0.125f);

    // 9) alpha = softmax(scores) -> planes + offArr
    softmax_alpha<<<B_ * H_ * R_, 256, 0, stream>>>(scoresOut, alphaH, alphaL, offArr);

    // 10) z1 = alpha @ vp_h : [256,64] x64, K=256 (B = vpT slice)
    gemm_pl<64, 0, 0, 2, false><<<dim3(1, 4, 64), 256, 0, stream>>>(
        P1(alphaH), P1(alphaL), P1(vpTH), P1(vpTL), P1(z1H), P1(z1L),
        R_, R_, R_, HD_, 8, llRR, (long long)64 * R_, 64, llHRR, llRHD, llRHD, 1.0f);

    // 11) z2 = z1 @ WO^T : [2048,512], K=512
    gemm_pl<64, 0, 0, 2, false><<<dim3(8, 32, 1), 256, 0, stream>>>(
        P1(z1H), P1(z1L), P1(WOH), P1(WOL), P1(z2H), P1(z2L),
        HD_, HD_, HD_, C_, 1, 0, 0, 0, 0, 0, 0, 1.0f);

    // 11b) z2T = transpose(z2) planes per batch: [R,C] -> [C,R]
    xpose_u16p<<<dim3(C_/64, R_/64, B_), 256, 0, stream>>>(
        z2H, z2L, z2TH, z2TL, R_, C_, llRC, llRC);

    // 12) z = pAlpha_ @ z2 : [2048,512] x8, K=256 (B = z2T)
    gemm_pl<64, 0, 0, 0, false><<<dim3(8, 32, 8), 256, 0, stream>>>(
        P1(pAlpha_H), P1(pAlpha_L), P1(z2TH), P1(z2TL), P1(zOut), N3,
        R_, R_, R_, C_, 8, llRL, llRC, llLC, 0, 0, 0, 1.0f);

    // 13) addLoss
    finalize_loss<<<1, 256, 0, stream>>>(addLossIn, loss, offArr, lossOut);
}

// Round 10
// 414.614 us; speedup vs baseline: 1.2104x; 1.0015x over previous
//
#include <hip/hip_runtime.h>

#define B_  8
#define L_  2048
#define C_  512
#define R_  256
#define H_  8
#define DK_ 64
#define HD_ 512
#define MASK_NEG (-32767.0f)

typedef __attribute__((ext_vector_type(8))) short short8;
typedef __attribute__((ext_vector_type(8))) unsigned short ushort8;
typedef __attribute__((ext_vector_type(4))) unsigned short ushort4_t;
typedef __attribute__((ext_vector_type(4))) float f32x4;
typedef unsigned short u16;

__device__ inline u16 bf16_rne(float x) {
    unsigned u = __float_as_uint(x);
    return (u16)((u + 0x7FFFu + ((u >> 16) & 1u)) >> 16);
}
// hi bf16 in low 16 bits, lo bf16 in high 16 bits
__device__ inline unsigned cvt_hl(float x) {
    u16 hh = bf16_rne(x);
    float hf = __uint_as_float(((unsigned)hh) << 16);
    u16 ll = bf16_rne(x - hf);
    return (unsigned)hh | ((unsigned)ll << 16);
}

struct Ptr3 { const void* p0; const void* p1; const void* p2; };

// ---------------- MFMA plane GEMM ----------------
// NTERM=3: C = scale * A @ B via Ah@Bh + Ah@Bl + Al@Bh (hi/lo split, fp32-class).
// NTERM=1: C = scale * Ah @ Bh (hi planes only — for loss Grams, error << threshold).
// AMODE: 0 = bf16 planes [M][K]; 2 = fp32 [M][K] (cvt on stage)
// BMODE: 0 = bf16 planes [N][K]
// EPI:   0 = store fp32 C*scale; 2 = store hi/lo planes
// Batch: z -> zb=z/divz, zh=z%divz. TRIPLE: zb picks pointer from Ptr3 (offset zh*sh);
//        else offsets zb*sb + zh*sh.
template<int BN, int AMODE, int BMODE, int EPI, bool TRIPLE, int NTERM = 3>
__global__ __launch_bounds__(256) void gemm_pl(
    Ptr3 aH, Ptr3 aL, Ptr3 bH, Ptr3 bL, Ptr3 cH, Ptr3 cL,
    int K, int lda, int ldb, int ldc, int divz,
    long long ash, long long bsh, long long csh,
    long long asb, long long bsb, long long csb,
    float scale)
{
    constexpr int NF = BN / 32;
    constexpr int XA = (NTERM == 3) ? 64 : 1;
    constexpr int XB = (NTERM == 3) ? BN : 1;
    __shared__ u16 Ahs[64][40], Als[XA][40];
    __shared__ u16 Bhs[BN][40], Bls[XB][40];

    const int z  = blockIdx.z;
    const int zb = z / divz, zh = z - zb * divz;
    const void* avH = TRIPLE ? (zb == 0 ? aH.p0 : zb == 1 ? aH.p1 : aH.p2) : aH.p0;
    const void* avL = TRIPLE ? (zb == 0 ? aL.p0 : zb == 1 ? aL.p1 : aL.p2) : aL.p0;
    const void* bvH = TRIPLE ? (zb == 0 ? bH.p0 : zb == 1 ? bH.p1 : bH.p2) : bH.p0;
    const void* bvL = TRIPLE ? (zb == 0 ? bL.p0 : zb == 1 ? bL.p1 : bL.p2) : bL.p0;
    void* cvH = (void*)(TRIPLE ? (zb == 0 ? cH.p0 : zb == 1 ? cH.p1 : cH.p2) : cH.p0);
    void* cvL = (void*)(TRIPLE ? (zb == 0 ? cL.p0 : zb == 1 ? cL.p1 : cL.p2) : cL.p0);
    const long long ao = (TRIPLE ? 0 : (long long)zb * asb) + (long long)zh * ash;
    const long long bo = (TRIPLE ? 0 : (long long)zb * bsb) + (long long)zh * bsh;
    const long long co = (TRIPLE ? 0 : (long long)zb * csb) + (long long)zh * csh;

    const u16*   AHg = (const u16*)avH + ao;
    const u16*   ALg = (const u16*)avL + ao;
    const float* Afg = (const float*)avH + ao;
    const u16*   BHg = (const u16*)bvH + bo;
    const u16*   BLg = (const u16*)bvL + bo;
    float* Cf  = (float*)cvH + co;
    u16*   CHg = (u16*)cvH + co;
    u16*   CLg = (u16*)cvL + co;

    const int m0 = blockIdx.y * 64, n0 = blockIdx.x * BN;
    const int tid = threadIdx.x;
    const int lane = tid & 63, w = tid >> 6;
    const int wrow = (w >> 1) * 32, wcol = (w & 1) * (BN / 2);
    const int l15 = lane & 15, lg = lane >> 4;

    f32x4 zero = {0.f, 0.f, 0.f, 0.f};
    f32x4 acc[2][NF];
    #pragma unroll
    for (int mf = 0; mf < 2; ++mf)
        #pragma unroll
        for (int nf = 0; nf < NF; ++nf) acc[mf][nf] = zero;

    for (int k0 = 0; k0 < K; k0 += 32) {
        // ---- stage A (64 x 32) ----
        if (AMODE == 0) {
            int row = tid >> 2, kc = (tid & 3) << 3;
            long long off = (long long)(m0 + row) * lda + (k0 + kc);
            *(ushort8*)&Ahs[row][kc] = *(const ushort8*)(AHg + off);
            if constexpr (NTERM == 3)
                *(ushort8*)&Als[row][kc] = *(const ushort8*)(ALg + off);
        } else { // AMODE == 2: fp32 [M][K]
            int row = tid >> 2, kc = (tid & 3) << 3;
            const float* s = Afg + (long long)(m0 + row) * lda + (k0 + kc);
            float4 v0 = *(const float4*)s, v1 = *(const float4*)(s + 4);
            unsigned p0 = cvt_hl(v0.x), p1 = cvt_hl(v0.y), p2 = cvt_hl(v0.z), p3 = cvt_hl(v0.w);
            unsigned p4 = cvt_hl(v1.x), p5 = cvt_hl(v1.y), p6 = cvt_hl(v1.z), p7 = cvt_hl(v1.w);
            ushort8 h, l;
            h[0]=(u16)p0; h[1]=(u16)p1; h[2]=(u16)p2; h[3]=(u16)p3;
            h[4]=(u16)p4; h[5]=(u16)p5; h[6]=(u16)p6; h[7]=(u16)p7;
            l[0]=(u16)(p0>>16); l[1]=(u16)(p1>>16); l[2]=(u16)(p2>>16); l[3]=(u16)(p3>>16);
            l[4]=(u16)(p4>>16); l[5]=(u16)(p5>>16); l[6]=(u16)(p6>>16); l[7]=(u16)(p7>>16);
            *(ushort8*)&Ahs[row][kc] = h;
            if constexpr (NTERM == 3)
                *(ushort8*)&Als[row][kc] = l;
        }
        // ---- stage B (BN x 32), planes [N][K] ----
        #pragma unroll
        for (int t = tid; t < BN * 4; t += 256) {
            int row = t >> 2, kc = (t & 3) << 3;
            long long off = (long long)(n0 + row) * ldb + (k0 + kc);
            *(ushort8*)&Bhs[row][kc] = *(const ushort8*)(BHg + off);
            if constexpr (NTERM == 3)
                *(ushort8*)&Bls[row][kc] = *(const ushort8*)(BLg + off);
        }
        __syncthreads();

        short8 a_h[2], a_l[2];
        a_h[0] = *(const short8*)&Ahs[wrow +      l15][lg * 8];
        a_h[1] = *(const short8*)&Ahs[wrow + 16 + l15][lg * 8];
        if constexpr (NTERM == 3) {
            a_l[0] = *(const short8*)&Als[wrow +      l15][lg * 8];
            a_l[1] = *(const short8*)&Als[wrow + 16 + l15][lg * 8];
        }
        #pragma unroll
        for (int nf = 0; nf < NF; ++nf) {
            short8 b_h = *(const short8*)&Bhs[wcol + nf * 16 + l15][lg * 8];
            if constexpr (NTERM == 3) {
                short8 b_l = *(const short8*)&Bls[wcol + nf * 16 + l15][lg * 8];
                #pragma unroll
                for (int mf = 0; mf < 2; ++mf) {
                    acc[mf][nf] = __builtin_amdgcn_mfma_f32_16x16x32_bf16(a_h[mf], b_h, acc[mf][nf], 0, 0, 0);
                    acc[mf][nf] = __builtin_amdgcn_mfma_f32_16x16x32_bf16(a_h[mf], b_l, acc[mf][nf], 0, 0, 0);
                    acc[mf][nf] = __builtin_amdgcn_mfma_f32_16x16x32_bf16(a_l[mf], b_h, acc[mf][nf], 0, 0, 0);
                }
            } else {
                #pragma unroll
                for (int mf = 0; mf < 2; ++mf)
                    acc[mf][nf] = __builtin_amdgcn_mfma_f32_16x16x32_bf16(a_h[mf], b_h, acc[mf][nf], 0, 0, 0);
            }
        }
        __syncthreads();
    }

    if (EPI == 0) {
        #pragma unroll
        for (int mf = 0; mf < 2; ++mf)
            #pragma unroll
            for (int nf = 0; nf < NF; ++nf) {
                int row = m0 + wrow + mf * 16 + lg * 4;
                int col = n0 + wcol + nf * 16 + l15;
                #pragma unroll
                for (int j = 0; j < 4; ++j)
                    Cf[(long long)(row + j) * ldc + col] = acc[mf][nf][j] * scale;
            }
    } else {
        #pragma unroll
        for (int mf = 0; mf < 2; ++mf)
            #pragma unroll
            for (int nf = 0; nf < NF; ++nf) {
                int row = m0 + wrow + mf * 16 + lg * 4;
                int col = n0 + wcol + nf * 16 + l15;
                #pragma unroll
                for (int j = 0; j < 4; ++j) {
                    unsigned p = cvt_hl(acc[mf][nf][j] * scale);
                    CHg[(long long)(row + j) * ldc + col] = (u16)p;
                    CLg[(long long)(row + j) * ldc + col] = (u16)(p >> 16);
                }
            }
    }
}

// ---------------- split-K loss reduce ----------------
// G partials: [KS][B][R][R] fp32. loss += sum over b, i!=j of (sum_ks Gpart)^2
#define KS_ 8
__global__ __launch_bounds__(256) void loss_reduce(
    const float* __restrict__ G, float* __restrict__ lossDst)
{
    __shared__ float red[4];
    const long long N = (long long)B_ * R_ * R_;
    float s = 0.0f;
    for (long long idx = (long long)blockIdx.x * 256 + threadIdx.x; idx < N;
         idx += (long long)gridDim.x * 256) {
        float g = 0.0f;
        #pragma unroll
        for (int ks = 0; ks < KS_; ++ks) g += G[(long long)ks * N + idx];
        int e = (int)(idx & (long long)(R_ * R_ - 1));
        int row = e >> 8, col = e & 255;
        if (row != col) s += g * g;
    }
    #pragma unroll
    for (int o = 32; o; o >>= 1) s += __shfl_down(s, o, 64);
    int lane = threadIdx.x & 63, wid = threadIdx.x >> 6;
    if (lane == 0) red[wid] = s;
    __syncthreads();
    if (threadIdx.x == 0) atomicAdd(lossDst, red[0] + red[1] + red[2] + red[3]);
}

// ---------------- transpose kernels ----------------
// fp32 [M][N] -> fp32 [N][M], batched over z
__global__ __launch_bounds__(256) void xpose_f32(
    const float* __restrict__ in, float* __restrict__ out,
    int M, int N, long long ibs, long long obs)
{
    __shared__ float S[64][65];
    const float* ip = in + (long long)blockIdx.z * ibs;
    float* op = out + (long long)blockIdx.z * obs;
    int n0 = blockIdx.x * 64, m0 = blockIdx.y * 64;
    int t = threadIdx.x;
    int c4 = (t & 15) << 2, rq = t >> 4;
    #pragma unroll
    for (int p = 0; p < 4; ++p) {
        int r = p * 16 + rq;
        float4 v = *(const float4*)(ip + (long long)(m0 + r) * N + n0 + c4);
        S[r][c4+0]=v.x; S[r][c4+1]=v.y; S[r][c4+2]=v.z; S[r][c4+3]=v.w;
    }
    __syncthreads();
    #pragma unroll
    for (int p = 0; p < 4; ++p) {
        int nr = p * 16 + rq;
        float4 o;
        o.x = S[c4+0][nr]; o.y = S[c4+1][nr]; o.z = S[c4+2][nr]; o.w = S[c4+3][nr];
        *(float4*)(op + (long long)(n0 + nr) * M + m0 + c4) = o;
    }
}

// fp32 [M][N] -> bf16 hi/lo planes [N][M], triple-batched: z -> (member, batch)
__global__ __launch_bounds__(256) void xpose_f32p3(
    Ptr3 src, Ptr3 dstH, Ptr3 dstL,
    int M, int N, long long ibs, long long obs, int divz)
{
    __shared__ float S[64][65];
    int z = blockIdx.z;
    int m = z / divz, b = z - m * divz;
    const float* ip = (const float*)(m == 0 ? src.p0 : m == 1 ? src.p1 : src.p2)
                      + (long long)b * ibs;
    u16* opH = (u16*)(m == 0 ? dstH.p0 : m == 1 ? dstH.p1 : dstH.p2) + (long long)b * obs;
    u16* opL = (u16*)(m == 0 ? dstL.p0 : m == 1 ? dstL.p1 : dstL.p2) + (long long)b * obs;
    int n0 = blockIdx.x * 64, m0 = blockIdx.y * 64;
    int t = threadIdx.x;
    int c4 = (t & 15) << 2, rq = t >> 4;
    #pragma unroll
    for (int p = 0; p < 4; ++p) {
        int r = p * 16 + rq;
        float4 v = *(const float4*)(ip + (long long)(m0 + r) * N + n0 + c4);
        S[r][c4+0]=v.x; S[r][c4+1]=v.y; S[r][c4+2]=v.z; S[r][c4+3]=v.w;
    }
    __syncthreads();
    #pragma unroll
    for (int p = 0; p < 4; ++p) {
        int nr = p * 16 + rq;
        unsigned q0 = cvt_hl(S[c4+0][nr]), q1 = cvt_hl(S[c4+1][nr]);
        unsigned q2 = cvt_hl(S[c4+2][nr]), q3 = cvt_hl(S[c4+3][nr]);
        ushort4_t h, l;
        h[0]=(u16)q0; h[1]=(u16)q1; h[2]=(u16)q2; h[3]=(u16)q3;
        l[0]=(u16)(q0>>16); l[1]=(u16)(q1>>16); l[2]=(u16)(q2>>16); l[3]=(u16)(q3>>16);
        long long ob = (long long)(n0 + nr) * M + m0 + c4;
        *(ushort4_t*)(opH + ob) = h;
        *(ushort4_t*)(opL + ob) = l;
    }
}

// u16 planes [M][N] -> planes [N][M], batched over z
__global__ __launch_bounds__(256) void xpose_u16p(
    const u16* __restrict__ inH, const u16* __restrict__ inL,
    u16* __restrict__ outH, u16* __restrict__ outL,
    int M, int N, long long ibs, long long obs)
{
    __shared__ u16 SH[64][66], SL[64][66];
    const u16* ipH = inH + (long long)blockIdx.z * ibs;
    const u16* ipL = inL + (long long)blockIdx.z * ibs;
    u16* opH = outH + (long long)blockIdx.z * obs;
    u16* opL = outL + (long long)blockIdx.z * obs;
    int n0 = blockIdx.x * 64, m0 = blockIdx.y * 64;
    int t = threadIdx.x;
    int c4 = (t & 15) << 2, rq = t >> 4;
    #pragma unroll
    for (int p = 0; p < 4; ++p) {
        int r = p * 16 + rq;
        long long ib = (long long)(m0 + r) * N + n0 + c4;
        ushort4_t vh = *(const ushort4_t*)(ipH + ib);
        ushort4_t vl = *(const ushort4_t*)(ipL + ib);
        SH[r][c4+0]=vh[0]; SH[r][c4+1]=vh[1]; SH[r][c4+2]=vh[2]; SH[r][c4+3]=vh[3];
        SL[r][c4+0]=vl[0]; SL[r][c4+1]=vl[1]; SL[r][c4+2]=vl[2]; SL[r][c4+3]=vl[3];
    }
    __syncthreads();
    #pragma unroll
    for (int p = 0; p < 4; ++p) {
        int nr = p * 16 + rq;
        ushort4_t h, l;
        h[0]=SH[c4+0][nr]; h[1]=SH[c4+1][nr]; h[2]=SH[c4+2][nr]; h[3]=SH[c4+3][nr];
        l[0]=SL[c4+0][nr]; l[1]=SL[c4+1][nr]; l[2]=SL[c4+2][nr]; l[3]=SL[c4+3][nr];
        long long ob = (long long)(n0 + nr) * M + m0 + c4;
        *(ushort4_t*)(opH + ob) = h;
        *(ushort4_t*)(opL + ob) = l;
    }
}

// ---------------- helpers ----------------
__device__ inline float waveMax(float v) {
    #pragma unroll
    for (int o = 32; o; o >>= 1) v = fmaxf(v, __shfl_xor(v, o, 64));
    return v;
}
__device__ inline float waveSum(float v) {
    #pragma unroll
    for (int o = 32; o; o >>= 1) v += __shfl_xor(v, o, 64);
    return v;
}

// fp32 -> hi/lo bf16 planes (for weights)
__global__ __launch_bounds__(256) void conv_planes(
    const float* __restrict__ src, u16* __restrict__ h, u16* __restrict__ l, int n4)
{
    int i = blockIdx.x * 256 + threadIdx.x;
    if (i >= n4) return;
    float4 v = ((const float4*)src)[i];
    unsigned p0 = cvt_hl(v.x), p1 = cvt_hl(v.y), p2 = cvt_hl(v.z), p3 = cvt_hl(v.w);
    ushort4_t hv, lv;
    hv[0]=(u16)p0; hv[1]=(u16)p1; hv[2]=(u16)p2; hv[3]=(u16)p3;
    lv[0]=(u16)(p0>>16); lv[1]=(u16)(p1>>16); lv[2]=(u16)(p2>>16); lv[3]=(u16)(p3>>16);
    ((ushort4_t*)h)[i] = hv;
    ((ushort4_t*)l)[i] = lv;
}

// pAlpha[b,r,:] = softmax over l of masked pScoreT[b,r,:] -> hi/lo planes
__global__ __launch_bounds__(256) void softmax_LT(
    const float* __restrict__ pT, const int* __restrict__ mask,
    u16* __restrict__ outH, u16* __restrict__ outL)
{
    __shared__ float sm[4], ss[4];
    int zi = blockIdx.x;              // b*R + r
    int b = zi >> 8;
    const float* row = pT + (long long)zi * L_;
    const int* mk = mask + (long long)b * L_ * L_;   // row 0 of [L,L]
    float vals[8];
    float mx = -3.4e38f;
    #pragma unroll
    for (int i = 0; i < 8; ++i) {
        int l = threadIdx.x + i * 256;
        float v = row[l];
        if (mk[l] == 0) v = MASK_NEG;
        vals[i] = v; mx = fmaxf(mx, v);
    }
    int lane = threadIdx.x & 63, wid = threadIdx.x >> 6;
    mx = waveMax(mx);
    if (lane == 0) sm[wid] = mx;
    __syncthreads();
    mx = fmaxf(fmaxf(sm[0], sm[1]), fmaxf(sm[2], sm[3]));
    float sum = 0.0f;
    #pragma unroll
    for (int i = 0; i < 8; ++i) { float e = __expf(vals[i] - mx); vals[i] = e; sum += e; }
    sum = waveSum(sum);
    if (lane == 0) ss[wid] = sum;
    __syncthreads();
    sum = ss[0] + ss[1] + ss[2] + ss[3];
    float inv = 1.0f / sum;
    long long base = (long long)zi * L_;
    #pragma unroll
    for (int i = 0; i < 8; ++i) {
        unsigned p = cvt_hl(vals[i] * inv);
        outH[base + threadIdx.x + i * 256] = (u16)p;
        outL[base + threadIdx.x + i * 256] = (u16)(p >> 16);
    }
}

// pAlpha_[b,l,:] = softmax over r of masked pScore[b,l,:] -> hi/lo planes
__global__ __launch_bounds__(256) void softmax_R(
    const float* __restrict__ pScore, const int* __restrict__ mask,
    u16* __restrict__ outH, u16* __restrict__ outL)
{
    __shared__ float sm[4], ss[4];
    long long z = blockIdx.x;    // b*L + l
    int b = (int)(z >> 11), l = (int)(z & 2047);
    bool pad = (mask[(long long)b * L_ * L_ + l] == 0);
    float v = pScore[z * R_ + threadIdx.x];
    if (pad) v = MASK_NEG;
    int lane = threadIdx.x & 63, wid = threadIdx.x >> 6;
    float mx = waveMax(v);
    if (lane == 0) sm[wid] = mx;
    __syncthreads();
    mx = fmaxf(fmaxf(sm[0], sm[1]), fmaxf(sm[2], sm[3]));
    float e = __expf(v - mx);
    float sum = waveSum(e);
    if (lane == 0) ss[wid] = sum;
    __syncthreads();
    sum = ss[0] + ss[1] + ss[2] + ss[3];
    unsigned p = cvt_hl(e / sum);
    outH[z * R_ + threadIdx.x] = (u16)p;
    outL[z * R_ + threadIdx.x] = (u16)(p >> 16);
}

// alpha = softmax(scores,-1) -> planes; per-row offdiag sum -> offArr[row]
__global__ __launch_bounds__(256) void softmax_alpha(
    const float* __restrict__ scores, u16* __restrict__ aH, u16* __restrict__ aL,
    float* __restrict__ offArr)
{
    __shared__ float sm[4], ss[4], so[4];
    long long row = blockIdx.x;  // over B*H*R
    int r = (int)(row & 255);
    float v = scores[row * 256 + threadIdx.x];
    int lane = threadIdx.x & 63, wid = threadIdx.x >> 6;
    float mx = waveMax(v);
    if (lane == 0) sm[wid] = mx;
    __syncthreads();
    mx = fmaxf(fmaxf(sm[0], sm[1]), fmaxf(sm[2], sm[3]));
    float e = __expf(v - mx);
    float sum = waveSum(e);
    if (lane == 0) ss[wid] = sum;
    __syncthreads();
    sum = ss[0] + ss[1] + ss[2] + ss[3];
    float a = e / sum;
    unsigned p = cvt_hl(a);
    aH[row * 256 + threadIdx.x] = (u16)p;
    aL[row * 256 + threadIdx.x] = (u16)(p >> 16);
    float off = (threadIdx.x == r) ? 0.0f : a;
    off = waveSum(off);
    if (lane == 0) so[wid] = off;
    __syncthreads();
    if (threadIdx.x == 0) offArr[row] = so[0] + so[1] + so[2] + so[3];
}

__global__ __launch_bounds__(256) void finalize_loss(
    const float* __restrict__ addLossIn, const float* __restrict__ lossAcc,
    const float* __restrict__ offArr, float* __restrict__ out)
{
    __shared__ float red[4];
    float s = 0.0f;
    for (int i = threadIdx.x; i < B_ * H_ * R_; i += 256) s += offArr[i];
    int lane = threadIdx.x & 63, wid = threadIdx.x >> 6;
    s = waveSum(s);
    if (lane == 0) red[wid] = s;
    __syncthreads();
    if (threadIdx.x == 0) {
        float total = red[0] + red[1] + red[2] + red[3];
        out[0] = addLossIn[0]
               + lossAcc[0] * (1.0f / ((float)B_ * R_ * R_))
               + total      * (1.0f / ((float)B_ * H_ * R_ * R_))
               + lossAcc[2] * (1.0f / ((float)B_ * R_ * R_));
    }
}

// ---------------- launch ----------------
extern "C" void kernel_launch(void* const* d_in, const int* in_sizes, int n_in,
                              void* d_out, int out_size, void* d_ws, size_t ws_size,
                              hipStream_t stream)
{
    const float* qx = (const float*)d_in[0];
    const float* kx = (const float*)d_in[1];
    const float* vx = (const float*)d_in[2];
    const float* addLossIn = (const float*)d_in[3];
    const int* mask = (const int*)d_in[4];
    const float* Wp = (const float*)d_in[5];
    const float* WQ = (const float*)d_in[6];
    const float* WK = (const float*)d_in[7];
    const float* WV = (const float*)d_in[8];
    const float* WO = (const float*)d_in[9];

    float* zOut      = (float*)d_out;                             // [B,L,C]
    float* scoresOut = zOut + (long long)B_ * L_ * C_;            // [B,H,R,R]
    float* lossOut   = scoresOut + (long long)B_ * H_ * R_ * R_;  // [1]

    const long long S = (long long)B_ * L_ * R_;    // 4,194,304
    const long long T = (long long)B_ * R_ * C_;    // 1,048,576
    u16* cur = (u16*)d_ws;
    auto takeU = [&](long long n) { u16* p = cur; cur += n; return p; };
    auto takeF = [&](long long n) { float* p = (float*)cur; cur += 2 * n; return p; };

    // ---- flat layout, no overlays (~265MB of 512MB ws) ----
    float* pScore   = takeF(S);          // [B,L,R]
    float* pScoreT  = takeF(S);          // [B,R,L]
    u16* pAlphaH  = takeU(S);            // [B,R,L]
    u16* pAlphaL  = takeU(S);
    u16* pAlpha_H = takeU(S);            // [B,L,R]
    u16* pAlpha_L = takeU(S);
    u16* pATH     = takeU(S);            // [B,R,L]
    u16* pATL     = takeU(S);
    u16* xTH0 = takeU(2*S); u16* xTL0 = takeU(2*S);   // [B,C,L] = 2S elems per plane
    u16* xTH1 = takeU(2*S); u16* xTL1 = takeU(2*S);
    u16* xTH2 = takeU(2*S); u16* xTL2 = takeU(2*S);
    float* Gpart  = takeF((long long)KS_ * B_ * R_ * R_);  // split-K partials
    u16* qrH = takeU(T); u16* qrL = takeU(T);
    u16* krH = takeU(T); u16* krL = takeU(T);
    u16* vrH = takeU(T); u16* vrL = takeU(T);
    u16* qpH = takeU(T); u16* qpL = takeU(T);
    u16* kpH = takeU(T); u16* kpL = takeU(T);
    u16* vpH = takeU(T); u16* vpL = takeU(T);
    u16* vpTH = takeU(T); u16* vpTL = takeU(T);
    u16* z1H = takeU(T); u16* z1L = takeU(T);
    u16* z2H = takeU(T); u16* z2L = takeU(T);
    u16* z2TH = takeU(T); u16* z2TL = takeU(T);
    u16* alphaH = takeU(S); u16* alphaL = takeU(S);   // [B,H,R,R] = S elems
    u16* WpH = takeU((long long)R_ * C_); u16* WpL = takeU((long long)R_ * C_);
    u16* WQH = takeU((long long)HD_ * C_); u16* WQL = takeU((long long)HD_ * C_);
    u16* WKH = takeU((long long)HD_ * C_); u16* WKL = takeU((long long)HD_ * C_);
    u16* WVH = takeU((long long)HD_ * C_); u16* WVL = takeU((long long)HD_ * C_);
    u16* WOH = takeU((long long)HD_ * C_); u16* WOL = takeU((long long)HD_ * C_);
    float* loss   = takeF(16);
    float* offArr = takeF(B_ * H_ * R_);

    const Ptr3 N3{nullptr, nullptr, nullptr};
    auto P1 = [](const void* p) { return Ptr3{p, p, p}; };
    const long long llRL = (long long)R_ * L_, llLC = (long long)L_ * C_;
    const long long llRC = (long long)R_ * C_, llRHD = (long long)R_ * HD_;
    const long long llRR = (long long)R_ * R_, llHRR = (long long)H_ * R_ * R_;
    const long long llCL = (long long)C_ * L_;

    (void)hipMemsetAsync(loss, 0, 3 * sizeof(float), stream);

    // 0) weights -> planes
    conv_planes<<<(R_*C_/4 + 255)/256, 256, 0, stream>>>(Wp, WpH, WpL, R_*C_/4);
    conv_planes<<<(HD_*C_/4 + 255)/256, 256, 0, stream>>>(WQ, WQH, WQL, HD_*C_/4);
    conv_planes<<<(HD_*C_/4 + 255)/256, 256, 0, stream>>>(WK, WKH, WKL, HD_*C_/4);
    conv_planes<<<(HD_*C_/4 + 255)/256, 256, 0, stream>>>(WV, WVH, WVL, HD_*C_/4);
    conv_planes<<<(HD_*C_/4 + 255)/256, 256, 0, stream>>>(WO, WOH, WOL, HD_*C_/4);

    // 1) pScore = vx @ Wp^T : [16384,256], K=512
    gemm_pl<128, 2, 0, 0, false><<<dim3(2, 256, 1), 256, 0, stream>>>(
        P1(vx), N3, P1(WpH), P1(WpL), P1(pScore), N3,
        C_, C_, C_, R_, 1, 0, 0, 0, 0, 0, 0, 1.0f);

    // 2) pScoreT = transpose(pScore) per batch
    xpose_f32<<<dim3(R_/64, L_/64, B_), 256, 0, stream>>>(
        pScore, pScoreT, L_, R_, llRL, llRL);

    // 3) softmaxes -> planes
    softmax_LT<<<B_ * R_, 256, 0, stream>>>(pScoreT, mask, pAlphaH, pAlphaL);
    softmax_R<<<B_ * L_, 256, 0, stream>>>(pScore, mask, pAlpha_H, pAlpha_L);

    // 3b) pAT = transpose(pAlpha_) planes: [L,R] -> [R,L]
    xpose_u16p<<<dim3(R_/64, L_/64, B_), 256, 0, stream>>>(
        pAlpha_H, pAlpha_L, pATH, pATL, L_, R_, llRL, llRL);

    // 4) loss1: split-K Gram, hi-plane only (error << threshold), BN=128
    gemm_pl<128, 0, 0, 0, false, 1><<<dim3(2, 4, KS_ * B_), 256, 0, stream>>>(
        P1(pAlphaH), N3, P1(pAlphaH), N3, P1(Gpart), N3,
        L_ / KS_, L_, L_, R_, B_,
        llRL, llRL, llRR,
        L_ / KS_, L_ / KS_, (long long)B_ * llRR, 1.0f);
    loss_reduce<<<64, 256, 0, stream>>>(Gpart, loss + 0);

    // 5) loss3: split-K Gram of pAT, hi-plane only, BN=128
    gemm_pl<128, 0, 0, 0, false, 1><<<dim3(2, 4, KS_ * B_), 256, 0, stream>>>(
        P1(pATH), N3, P1(pATH), N3, P1(Gpart), N3,
        L_ / KS_, L_, L_, R_, B_,
        llRL, llRL, llRR,
        L_ / KS_, L_ / KS_, (long long)B_ * llRR, 1.0f);
    loss_reduce<<<64, 256, 0, stream>>>(Gpart, loss + 2);

    // 6) xT = transpose all three inputs -> planes [C][L] (one launch, z=24)
    xpose_f32p3<<<dim3(C_/64, L_/64, 3 * B_), 256, 0, stream>>>(
        Ptr3{qx, kx, vx}, Ptr3{xTH0, xTH1, xTH2}, Ptr3{xTL0, xTL1, xTL2},
        L_, C_, llLC, llCL, B_);

    // 6b) {q,k,v}r = pAlpha @ x : triple-fused, BN=128 (halves A panel refetch)
    gemm_pl<128, 0, 0, 2, true><<<dim3(C_/128, R_/64, 3 * B_), 256, 0, stream>>>(
        P1(pAlphaH), P1(pAlphaL),
        Ptr3{xTH0, xTH1, xTH2}, Ptr3{xTL0, xTL1, xTL2},
        Ptr3{qrH, krH, vrH}, Ptr3{qrL, krL, vrL},
        L_, L_, L_, C_, B_, llRL, llCL, llRC, 0, 0, 0, 1.0f);

    // 7) projections: {qp,kp,vp} = {qr,kr,vr} @ {WQ,WK,WV}^T : [2048,512], K=512 (triple)
    gemm_pl<64, 0, 0, 2, true><<<dim3(8, 32, 3), 256, 0, stream>>>(
        Ptr3{qrH, krH, vrH}, Ptr3{qrL, krL, vrL},
        Ptr3{WQH, WKH, WVH}, Ptr3{WQL, WKL, WVL},
        Ptr3{qpH, kpH, vpH}, Ptr3{qpL, kpL, vpL},
        C_, C_, C_, HD_, 1, 0, 0, 0, 0, 0, 0, 1.0f);

    // 7b) vpT = transpose(vp) planes per batch: [R,HD] -> [HD,R]
    xpose_u16p<<<dim3(HD_/64, R_/64, B_), 256, 0, stream>>>(
        vpH, vpL, vpTH, vpTL, R_, HD_, llRHD, llRHD);

    // 8) scores = qp_h @ kp_h^T / 8 : [256,256] x64, K=64
    gemm_pl<64, 0, 0, 0, false><<<dim3(4, 4, 64), 256, 0, stream>>>(
        P1(qpH), P1(qpL), P1(kpH), P1(kpL), P1(scoresOut), N3,
        DK_, HD_, HD_, R_, 8, 64, 64, llRR, llRHD, llRHD, llHRR, 0.125f);

    // 9) alpha = softmax(scores) -> planes + offArr
    softmax_alpha<<<B_ * H_ * R_, 256, 0, stream>>>(scoresOut, alphaH, alphaL, offArr);

    // 10) z1 = alpha @ vp_h : [256,64] x64, K=256 (B = vpT slice)
    gemm_pl<64, 0, 0, 2, false><<<dim3(1, 4, 64), 256, 0, stream>>>(
        P1(alphaH), P1(alphaL), P1(vpTH), P1(vpTL), P1(z1H), P1(z1L),
        R_, R_, R_, HD_, 8, llRR, (long long)64 * R_, 64, llHRR, llRHD, llRHD, 1.0f);

    // 11) z2 = z1 @ WO^T : [2048,512], K=512
    gemm_pl<64, 0, 0, 2, false><<<dim3(8, 32, 1), 256, 0, stream>>>(
        P1(z1H), P1(z1L), P1(WOH), P1(WOL), P1(z2H), P1(z2L),
        HD_, HD_, HD_, C_, 1, 0, 0, 0, 0, 0, 0, 1.0f);

    // 11b) z2T = transpose(z2) planes per batch: [R,C] -> [C,R]
    xpose_u16p<<<dim3(C_/64, R_/64, B_), 256, 0, stream>>>(
        z2H, z2L, z2TH, z2TL, R_, C_, llRC, llRC);

    // 12) z = pAlpha_ @ z2 : [2048,512] x8, K=256 (B = z2T)
    gemm_pl<64, 0, 0, 0, false><<<dim3(8, 32, 8), 256, 0, stream>>>(
        P1(pAlpha_H), P1(pAlpha_L), P1(z2TH), P1(z2TL), P1(zOut), N3,
        R_, R_, R_, C_, 8, llRL, llRC, llLC, 0, 0, 0, 1.0f);

    // 13) addLoss
    finalize_loss<<<1, 256, 0, stream>>>(addLossIn, loss, offArr, lossOut);
}